// Round 1
// baseline (409.673 us; speedup 1.0000x reference)
//
#include <hip/hip_runtime.h>

// AttentionBlock: x[4,2048,1024] fp32; scores = x@(Wq@Wk^T)@x^T (NO scale);
// softmax; out = P@(x@Wv).
// M' = Wk@Wq^T -> y = x@M'^T replaces both q,k projections; scores = y@x^T.
// Split-f16 (hi+lo, 3-MFMA) for M', y, scores; plain f16 for v, PV.
// Round 10: scores GEMM rewritten as 256x256-tile 8-phase schedule
// (counted vmcnt(4), LDS chunk swizzle, setprio) over segmented K'=3072:
// seg0 = yh*xh, seg1 = yh*xl, seg2 = yl*xh  == the 3-MFMA split, but the
// hot loop is a plain f16 GEMM (T2+T3+T4+T5 per the 8-phase template).
// Confirmed dead ends: 128x256 tiles (r4/r5), 32x32x16 MFMA (r6: bank
// conflicts 3x), direct-to-VGPR lo loads (r7), BK=64 in old structure (r6).

typedef _Float16 half4_t __attribute__((ext_vector_type(4)));
typedef _Float16 half8_t __attribute__((ext_vector_type(8)));
typedef float f32x4 __attribute__((ext_vector_type(4)));

#define BM 128
#define BN 128
#define BK 32

__device__ __forceinline__ void gl_lds16(const _Float16* g, _Float16* l) {
    __builtin_amdgcn_global_load_lds(
        (const __attribute__((address_space(1))) unsigned int*)g,
        (__attribute__((address_space(3))) unsigned int*)l, 16, 0, 0);
}

// ---------------- merged conversion kernel (flat 1D grid) ----------------
__global__ __launch_bounds__(256) void conv_all_kernel(
    const float* __restrict__ x, const float* __restrict__ wq,
    const float* __restrict__ wk, const float* __restrict__ wv,
    _Float16* __restrict__ xh, _Float16* __restrict__ xl,
    _Float16* __restrict__ qh, _Float16* __restrict__ ql,
    _Float16* __restrict__ kh, _Float16* __restrict__ kl,
    _Float16* __restrict__ vTh)
{
    __shared__ float tle[64][65];
    const int bid = blockIdx.x;
    if (bid < 10240) {
        const float* in;
        _Float16 *hi, *lo;
        int i0;
        if (bid < 8192)      { in = x;  hi = xh; lo = xl; i0 = bid; }
        else if (bid < 9216) { in = wq; hi = qh; lo = ql; i0 = bid - 8192; }
        else                 { in = wk; hi = kh; lo = kl; i0 = bid - 9216; }
        int i = i0 * 256 + threadIdx.x;
        float4 v = ((const float4*)in)[i];
        float xs[4] = {v.x, v.y, v.z, v.w};
        half4_t h, l;
#pragma unroll
        for (int j = 0; j < 4; ++j) {
            _Float16 hh = (_Float16)xs[j];
            h[j] = hh;
            l[j] = (_Float16)(xs[j] - (float)hh);
        }
        ((half4_t*)hi)[i] = h;
        ((half4_t*)lo)[i] = l;
    } else {
        const int t = bid - 10240;
        const int tr = (t >> 4) * 64, tc = (t & 15) * 64;
        const int t16 = threadIdx.x & 15, tq = threadIdx.x >> 4;
#pragma unroll
        for (int j = 0; j < 4; ++j) {
            int lr = tq + j * 16;
            float4 v = *(const float4*)(wv + (size_t)(tr + lr) * 1024 + tc + t16 * 4);
            tle[lr][t16 * 4 + 0] = v.x;
            tle[lr][t16 * 4 + 1] = v.y;
            tle[lr][t16 * 4 + 2] = v.z;
            tle[lr][t16 * 4 + 3] = v.w;
        }
        __syncthreads();
#pragma unroll
        for (int j = 0; j < 4; ++j) {
            int orow = tq + j * 16;
            int oc = t16 * 4;
            half4_t h;
#pragma unroll
            for (int i = 0; i < 4; ++i) h[i] = (_Float16)tle[oc + i][orow];
            *(half4_t*)(vTh + (size_t)(tc + orow) * 1024 + tr + oc) = h;
        }
    }
}

// ---------------- split-f16 GEMM (3-MFMA, 16x16x32), 128x128 (M' only) ----------------
template <bool OUTF32>
__global__ __launch_bounds__(256) void gemm_split(
    const _Float16* __restrict__ Ah, const _Float16* __restrict__ Al, size_t az,
    const _Float16* __restrict__ Bh, const _Float16* __restrict__ Bl, size_t bz,
    float* __restrict__ Cf, size_t cz, int ldc,
    _Float16* __restrict__ Oh, _Float16* __restrict__ Ol, size_t oz, int ldo,
    int lda, int ldb, int K)
{
    __shared__ __align__(16) _Float16 sAh[BM][BK], sAl[BM][BK];
    __shared__ __align__(16) _Float16 sBh[BN][BK], sBl[BN][BK];

    const int tid = threadIdx.x;
    const int wave = tid >> 6, lane = tid & 63;
    const int wm = (wave >> 1) * 64, wn = (wave & 1) * 64;
    const int lrow = lane & 15, quad = lane >> 4;
    const int bm = blockIdx.y * BM, bn = blockIdx.x * BN;
    const int z = blockIdx.z;

    const _Float16* pAh = Ah + (size_t)z * az;
    const _Float16* pAl = Al + (size_t)z * az;
    const _Float16* pBh = Bh + (size_t)z * bz;
    const _Float16* pBl = Bl + (size_t)z * bz;

    const int r0 = wave * 32 + (lane >> 2);
    const int kofs = (lane & 3) * 8;
    const size_t a0o = (size_t)(bm + r0) * lda + kofs;
    const size_t a1o = a0o + (size_t)16 * lda;
    const size_t b0o = (size_t)(bn + r0) * ldb + kofs;
    const size_t b1o = b0o + (size_t)16 * ldb;
    _Float16* lA0 = &sAh[r0][kofs];
    _Float16* lA1 = &sAh[r0 + 16][kofs];
    _Float16* lAl0 = &sAl[r0][kofs];
    _Float16* lAl1 = &sAl[r0 + 16][kofs];
    _Float16* lB0 = &sBh[r0][kofs];
    _Float16* lB1 = &sBh[r0 + 16][kofs];
    _Float16* lBl0 = &sBl[r0][kofs];
    _Float16* lBl1 = &sBl[r0 + 16][kofs];

    f32x4 acc[4][4];
#pragma unroll
    for (int i = 0; i < 4; ++i)
#pragma unroll
        for (int j = 0; j < 4; ++j) acc[i][j] = 0.0f;

    for (int k0 = 0; k0 < K; k0 += BK) {
        gl_lds16(pAh + a0o + k0, lA0);
        gl_lds16(pAh + a1o + k0, lA1);
        gl_lds16(pAl + a0o + k0, lAl0);
        gl_lds16(pAl + a1o + k0, lAl1);
        gl_lds16(pBh + b0o + k0, lB0);
        gl_lds16(pBh + b1o + k0, lB1);
        gl_lds16(pBl + b0o + k0, lBl0);
        gl_lds16(pBl + b1o + k0, lBl1);
        __syncthreads();

        half8_t a0[4], a1[4], b0[4], b1[4];
#pragma unroll
        for (int mt = 0; mt < 4; ++mt) {
            a0[mt] = *(const half8_t*)&sAh[wm + mt * 16 + lrow][quad * 8];
            a1[mt] = *(const half8_t*)&sAl[wm + mt * 16 + lrow][quad * 8];
        }
#pragma unroll
        for (int nt = 0; nt < 4; ++nt) {
            b0[nt] = *(const half8_t*)&sBh[wn + nt * 16 + lrow][quad * 8];
            b1[nt] = *(const half8_t*)&sBl[wn + nt * 16 + lrow][quad * 8];
        }
#pragma unroll
        for (int mt = 0; mt < 4; ++mt)
#pragma unroll
            for (int nt = 0; nt < 4; ++nt) {
                acc[mt][nt] = __builtin_amdgcn_mfma_f32_16x16x32_f16(a0[mt], b0[nt], acc[mt][nt], 0, 0, 0);
                acc[mt][nt] = __builtin_amdgcn_mfma_f32_16x16x32_f16(a0[mt], b1[nt], acc[mt][nt], 0, 0, 0);
                acc[mt][nt] = __builtin_amdgcn_mfma_f32_16x16x32_f16(a1[mt], b0[nt], acc[mt][nt], 0, 0, 0);
            }
        __syncthreads();
    }

#pragma unroll
    for (int mt = 0; mt < 4; ++mt)
#pragma unroll
        for (int nt = 0; nt < 4; ++nt)
#pragma unroll
            for (int r = 0; r < 4; ++r) {
                int gm = bm + wm + mt * 16 + quad * 4 + r;
                int gn = bn + wn + nt * 16 + lrow;
                float v = acc[mt][nt][r];
                if (OUTF32) {
                    Cf[(size_t)z * cz + (size_t)gm * ldc + gn] = v;
                } else {
                    _Float16 h = (_Float16)v;
                    Oh[(size_t)z * oz + (size_t)gm * ldo + gn] = h;
                    Ol[(size_t)z * oz + (size_t)gm * ldo + gn] = (_Float16)(v - (float)h);
                }
            }
}

// ---------------- scores: 256x256-tile 8-phase GEMM, segmented K'=3072 ----------------
// C[s][t] = sum_seg A_seg[s][k] * B_seg[t][k], segs = (yh,xh),(yh,xl),(yl,xh).
// 512 threads = 8 waves (2M x 4N); per-wave C = 128x64 (8x4 16x16 frags).
// LDS: 4 half-slots per operand (2 dbuf x 2 K-halves), 16KB each = 128KB.
// Chunk swizzle: 16B chunk of (row, j) stored at F = row*4 + (j ^ ((row>>1)&3))
// -> 2-way max bank aliasing on ds_read_b128 (free), applied to BOTH the
// staging source address and the read address (linear gl_lds dest).
// Per K-tile: 4 phases {ds_read subtile | stage 1 half-tile | barrier |
// setprio(1) 16 MFMA setprio(0) | barrier}; ONE vmcnt(4) per tile (2
// half-tiles = 4 loads stay in flight across barriers; never drain to 0).
#define NTILES 48  // 3072 / 64

__global__ __launch_bounds__(512, 2) void scores_8ph(
    const _Float16* __restrict__ yh, const _Float16* __restrict__ yl,
    const _Float16* __restrict__ xh, const _Float16* __restrict__ xl,
    float* __restrict__ Cf)
{
    __shared__ __align__(16) _Float16 sA[4][8192];  // 64KB
    __shared__ __align__(16) _Float16 sB[4][8192];  // 64KB

    const int tid = threadIdx.x;
    const int wave = tid >> 6, lane = tid & 63;
    const int wm = (wave >> 2) * 128;      // 2 wave-rows
    const int wn = (wave & 3) * 64;        // 4 wave-cols
    const int l15 = lane & 15, jq = lane >> 4;
    const int z = blockIdx.z;
    const int bm = blockIdx.y * 256, bn = blockIdx.x * 256;

    const _Float16* Ah = yh + ((size_t)z * 2048 + bm) * 1024;
    const _Float16* Al = yl + ((size_t)z * 2048 + bm) * 1024;
    const _Float16* Bh = xh + ((size_t)z * 2048 + bn) * 1024;
    const _Float16* Bl = xl + ((size_t)z * 2048 + bn) * 1024;

    // stage one 16KB half-tile (256 rows x 32 k of one K-half): 2 loads/thread
    auto stage = [&](const _Float16* base, int tloc, int khalf, _Float16* slot) {
#pragma unroll
        for (int i = 0; i < 2; ++i) {
            int c = i * 512 + tid;          // chunk index this thread fills
            int row = c >> 2;
            int j = (c & 3) ^ ((row >> 1) & 3);   // inverse of read swizzle
            gl_lds16(base + (size_t)row * 1024 + tloc * 64 + khalf * 32 + j * 8,
                     slot + c * 8);
        }
    };
    // segment plane selection: t in [0,16)->(Ah,Bh); [16,32)->(Ah,Bl); [32,48)->(Al,Bh)
    auto aseg = [&](int t) { return t < 32 ? Ah : Al; };
    auto bseg = [&](int t) { return (t >> 4) == 1 ? Bl : Bh; };
    // swizzled fragment read: lane l15 -> row, jq -> k-subchunk
    auto frag = [&](const _Float16* slot, int row) {
        int F = row * 4 + (jq ^ ((row >> 1) & 3));
        return *(const half8_t*)(slot + F * 8);
    };

    f32x4 acc[8][4];
#pragma unroll
    for (int i = 0; i < 8; ++i)
#pragma unroll
        for (int j = 0; j < 4; ++j) acc[i][j] = 0.0f;

    // prologue: tile0 (both K-halves) + tile1 (K-half 0) = 6 half-tiles (12 loads)
    stage(aseg(0), 0, 0, sA[0]);
    stage(bseg(0), 0, 0, sB[0]);
    stage(aseg(0), 0, 1, sA[1]);
    stage(bseg(0), 0, 1, sB[1]);
    stage(aseg(1), 1, 0, sA[2]);
    stage(bseg(1), 1, 0, sB[2]);
    // wait tile0 fully resident (last 2 half-tiles may stay in flight)
    asm volatile("s_waitcnt vmcnt(4)\n\ts_barrier" ::: "memory");

    for (int t = 0; t < NTILES; ++t) {
        const int t1 = (t + 1 < NTILES) ? t + 1 : NTILES - 1;  // clamped re-stage
        const int t2 = (t + 2 < NTILES) ? t + 2 : NTILES - 1;  // (identical bytes)
        _Float16* a0s = sA[(t & 1) * 2 + 0];
        _Float16* b0s = sB[(t & 1) * 2 + 0];
        _Float16* a1s = sA[(t & 1) * 2 + 1];
        _Float16* b1s = sB[(t & 1) * 2 + 1];
        half8_t aa[4], bb[4];

        // ---- q0: frags-half0 x khalf0; stage A-kh1(t+1)
#pragma unroll
        for (int n = 0; n < 4; ++n) bb[n] = frag(b0s, wn + n * 16 + l15);
#pragma unroll
        for (int m = 0; m < 4; ++m) aa[m] = frag(a0s, wm + m * 16 + l15);
        stage(aseg(t1), t1 & 15, 1, sA[(t1 & 1) * 2 + 1]);
        asm volatile("s_barrier" ::: "memory");
        __builtin_amdgcn_s_setprio(1);
#pragma unroll
        for (int m = 0; m < 4; ++m)
#pragma unroll
            for (int n = 0; n < 4; ++n)
                acc[m][n] = __builtin_amdgcn_mfma_f32_16x16x32_f16(aa[m], bb[n], acc[m][n], 0, 0, 0);
        __builtin_amdgcn_s_setprio(0);
        __builtin_amdgcn_sched_barrier(0);
        asm volatile("s_barrier" ::: "memory");

        // ---- q1: frags-half1 x khalf0; stage B-kh1(t+1); reuse bb
#pragma unroll
        for (int m = 0; m < 4; ++m) aa[m] = frag(a0s, wm + 64 + m * 16 + l15);
        stage(bseg(t1), t1 & 15, 1, sB[(t1 & 1) * 2 + 1]);
        asm volatile("s_barrier" ::: "memory");
        __builtin_amdgcn_s_setprio(1);
#pragma unroll
        for (int m = 0; m < 4; ++m)
#pragma unroll
            for (int n = 0; n < 4; ++n)
                acc[4 + m][n] = __builtin_amdgcn_mfma_f32_16x16x32_f16(aa[m], bb[n], acc[4 + m][n], 0, 0, 0);
        __builtin_amdgcn_s_setprio(0);
        __builtin_amdgcn_sched_barrier(0);
        asm volatile("s_barrier" ::: "memory");

        // ---- q2: frags-half0 x khalf1; stage A-kh0(t+2)
#pragma unroll
        for (int n = 0; n < 4; ++n) bb[n] = frag(b1s, wn + n * 16 + l15);
#pragma unroll
        for (int m = 0; m < 4; ++m) aa[m] = frag(a1s, wm + m * 16 + l15);
        stage(aseg(t2), t2 & 15, 0, sA[(t2 & 1) * 2 + 0]);
        asm volatile("s_barrier" ::: "memory");
        __builtin_amdgcn_s_setprio(1);
#pragma unroll
        for (int m = 0; m < 4; ++m)
#pragma unroll
            for (int n = 0; n < 4; ++n)
                acc[m][n] = __builtin_amdgcn_mfma_f32_16x16x32_f16(aa[m], bb[n], acc[m][n], 0, 0, 0);
        __builtin_amdgcn_s_setprio(0);
        __builtin_amdgcn_sched_barrier(0);
        asm volatile("s_barrier" ::: "memory");

        // ---- q3: frags-half1 x khalf1; stage B-kh0(t+2); vmcnt checkpoint
#pragma unroll
        for (int m = 0; m < 4; ++m) aa[m] = frag(a1s, wm + 64 + m * 16 + l15);
        stage(bseg(t2), t2 & 15, 0, sB[(t2 & 1) * 2 + 0]);
        asm volatile("s_barrier" ::: "memory");
        __builtin_amdgcn_s_setprio(1);
#pragma unroll
        for (int m = 0; m < 4; ++m)
#pragma unroll
            for (int n = 0; n < 4; ++n)
                acc[4 + m][n] = __builtin_amdgcn_mfma_f32_16x16x32_f16(aa[m], bb[n], acc[4 + m][n], 0, 0, 0);
        __builtin_amdgcn_s_setprio(0);
        __builtin_amdgcn_sched_barrier(0);
        // tile t+1 must be fully resident after this; only the 2 half-tiles
        // issued at q2/q3 (4 loads) may remain in flight. NEVER vmcnt(0) here.
        asm volatile("s_waitcnt vmcnt(4)\n\ts_barrier" ::: "memory");
    }
    asm volatile("s_waitcnt vmcnt(0)" ::: "memory");

    // epilogue: fp32 C scatter (same layout as verified gemm_split)
    float* C = Cf + (size_t)z * 2048 * 2048;
#pragma unroll
    for (int mi = 0; mi < 8; ++mi)
#pragma unroll
        for (int ni = 0; ni < 4; ++ni) {
            int gm0 = bm + wm + mi * 16 + jq * 4;
            int gn = bn + wn + ni * 16 + l15;
#pragma unroll
            for (int r = 0; r < 4; ++r)
                C[(size_t)(gm0 + r) * 2048 + gn] = acc[mi][ni][r];
        }
}

// ---------------- merged y-proj (split) + v-proj (plain) kernel ----------------
__global__ __launch_bounds__(256) void yv_kernel(
    const _Float16* __restrict__ xh, const _Float16* __restrict__ xl,
    const _Float16* __restrict__ Mh, const _Float16* __restrict__ Ml,
    const _Float16* __restrict__ wvTh,
    _Float16* __restrict__ yh, _Float16* __restrict__ yl,
    _Float16* __restrict__ vT)
{
    __shared__ __align__(16) char buf[128 * 132 * 2];  // 33792 B

    const int tid = threadIdx.x;
    const int wave = tid >> 6, lane = tid & 63;
    const int wm = (wave >> 1) * 64, wn = (wave & 1) * 64;
    const int lrow = lane & 15, quad = lane >> 4;
    const int bm = blockIdx.y * BM, bn = blockIdx.x * BN;
    const bool vrole = (blockIdx.z != 0);

    const int r0 = wave * 32 + (lane >> 2);
    const int kofs = (lane & 3) * 8;
    const size_t a0o = (size_t)(bm + r0) * 1024 + kofs;
    const size_t a1o = a0o + (size_t)16 * 1024;
    const size_t b0o = (size_t)(bn + r0) * 1024 + kofs;
    const size_t b1o = b0o + (size_t)16 * 1024;

    f32x4 acc[4][4];
#pragma unroll
    for (int i = 0; i < 4; ++i)
#pragma unroll
        for (int j = 0; j < 4; ++j) acc[i][j] = 0.0f;

    _Float16* tle = (_Float16*)buf;

    if (!vrole) {
        _Float16* sAh = (_Float16*)buf;
        _Float16* sAl = (_Float16*)(buf + 8192);
        _Float16* sBh = (_Float16*)(buf + 16384);
        _Float16* sBl = (_Float16*)(buf + 24576);
        _Float16* lA0 = sAh + r0 * BK + kofs;
        _Float16* lA1 = sAh + (r0 + 16) * BK + kofs;
        _Float16* lAl0 = sAl + r0 * BK + kofs;
        _Float16* lAl1 = sAl + (r0 + 16) * BK + kofs;
        _Float16* lB0 = sBh + r0 * BK + kofs;
        _Float16* lB1 = sBh + (r0 + 16) * BK + kofs;
        _Float16* lBl0 = sBl + r0 * BK + kofs;
        _Float16* lBl1 = sBl + (r0 + 16) * BK + kofs;

        for (int k0 = 0; k0 < 1024; k0 += BK) {
            gl_lds16(xh + a0o + k0, lA0);
            gl_lds16(xh + a1o + k0, lA1);
            gl_lds16(xl + a0o + k0, lAl0);
            gl_lds16(xl + a1o + k0, lAl1);
            gl_lds16(Mh + b0o + k0, lB0);
            gl_lds16(Mh + b1o + k0, lB1);
            gl_lds16(Ml + b0o + k0, lBl0);
            gl_lds16(Ml + b1o + k0, lBl1);
            __syncthreads();

            half8_t a0[4], a1[4], b0[4], b1[4];
#pragma unroll
            for (int mt = 0; mt < 4; ++mt) {
                a0[mt] = *(const half8_t*)(sAh + (wm + mt * 16 + lrow) * BK + quad * 8);
                a1[mt] = *(const half8_t*)(sAl + (wm + mt * 16 + lrow) * BK + quad * 8);
            }
#pragma unroll
            for (int nt = 0; nt < 4; ++nt) {
                b0[nt] = *(const half8_t*)(sBh + (wn + nt * 16 + lrow) * BK + quad * 8);
                b1[nt] = *(const half8_t*)(sBl + (wn + nt * 16 + lrow) * BK + quad * 8);
            }
#pragma unroll
            for (int mt = 0; mt < 4; ++mt)
#pragma unroll
                for (int nt = 0; nt < 4; ++nt) {
                    acc[mt][nt] = __builtin_amdgcn_mfma_f32_16x16x32_f16(a0[mt], b0[nt], acc[mt][nt], 0, 0, 0);
                    acc[mt][nt] = __builtin_amdgcn_mfma_f32_16x16x32_f16(a0[mt], b1[nt], acc[mt][nt], 0, 0, 0);
                    acc[mt][nt] = __builtin_amdgcn_mfma_f32_16x16x32_f16(a1[mt], b0[nt], acc[mt][nt], 0, 0, 0);
                }
            __syncthreads();
        }

#pragma unroll
        for (int pass = 0; pass < 2; ++pass) {
            if (pass) __syncthreads();
#pragma unroll
            for (int mt = 0; mt < 4; ++mt)
#pragma unroll
                for (int nt = 0; nt < 4; ++nt) {
                    int rloc = wm + mt * 16 + quad * 4;
                    int cloc = wn + nt * 16 + lrow;
#pragma unroll
                    for (int r = 0; r < 4; ++r) {
                        float v = acc[mt][nt][r];
                        _Float16 h = (_Float16)v;
                        tle[(rloc + r) * 132 + cloc] =
                            pass == 0 ? h : (_Float16)(v - (float)h);
                    }
                }
            __syncthreads();
            _Float16* dst = pass == 0 ? yh : yl;
#pragma unroll
            for (int i = 0; i < 8; ++i) {
                int flat = i * 256 + tid;
                int rloc = flat >> 4, c = (flat & 15) * 8;
                half8_t o8;
#pragma unroll
                for (int j = 0; j < 8; ++j) o8[j] = tle[rloc * 132 + c + j];
                *(half8_t*)(dst + (size_t)(bm + rloc) * 1024 + bn + c) = o8;
            }
        }
    } else {
        _Float16* sA = (_Float16*)buf;
        _Float16* sB = (_Float16*)(buf + 8192);
        _Float16* lA0 = sA + r0 * BK + kofs;
        _Float16* lA1 = sA + (r0 + 16) * BK + kofs;
        _Float16* lB0 = sB + r0 * BK + kofs;
        _Float16* lB1 = sB + (r0 + 16) * BK + kofs;

        for (int k0 = 0; k0 < 1024; k0 += BK) {
            gl_lds16(xh + a0o + k0, lA0);
            gl_lds16(xh + a1o + k0, lA1);
            gl_lds16(wvTh + b0o + k0, lB0);
            gl_lds16(wvTh + b1o + k0, lB1);
            __syncthreads();

            half8_t a0[4], b0[4];
#pragma unroll
            for (int mt = 0; mt < 4; ++mt)
                a0[mt] = *(const half8_t*)(sA + (wm + mt * 16 + lrow) * BK + quad * 8);
#pragma unroll
            for (int nt = 0; nt < 4; ++nt)
                b0[nt] = *(const half8_t*)(sB + (wn + nt * 16 + lrow) * BK + quad * 8);
#pragma unroll
            for (int mt = 0; mt < 4; ++mt)
#pragma unroll
                for (int nt = 0; nt < 4; ++nt)
                    acc[mt][nt] = __builtin_amdgcn_mfma_f32_16x16x32_f16(a0[mt], b0[nt], acc[mt][nt], 0, 0, 0);
            __syncthreads();
        }

#pragma unroll
        for (int mt = 0; mt < 4; ++mt)
#pragma unroll
            for (int nt = 0; nt < 4; ++nt) {
                int t0 = wm + mt * 16 + quad * 4;
                int e_l = wn + nt * 16 + lrow;
                half4_t o;
#pragma unroll
                for (int r = 0; r < 4; ++r) o[r] = (_Float16)acc[mt][nt][r];
                *(half4_t*)(tle + e_l * 132 + t0) = o;
            }
        __syncthreads();
        const int b = bm >> 11, tb = bm & 2047;
#pragma unroll
        for (int i = 0; i < 8; ++i) {
            int flat = i * 256 + tid;
            int e_l = flat >> 4, c = (flat & 15) * 8;
            half8_t o8;
#pragma unroll
            for (int j = 0; j < 8; ++j) o8[j] = tle[e_l * 132 + c + j];
            *(half8_t*)(vT + ((size_t)b << 21) + (size_t)(bn + e_l) * 2048 + tb + c) = o8;
        }
    }
}

// ---------------- plain-f16 GEMM (16x16x32), 128x128, 256 thr (PV) ----------------
__global__ __launch_bounds__(256) void gemm_plain(
    const _Float16* __restrict__ Ag, size_t az,
    const _Float16* __restrict__ Bg, size_t bz,
    float* __restrict__ Cf, size_t cz, int ldc,
    int lda, int ldb, int K)
{
    __shared__ __align__(16) _Float16 sA[BM][BK], sB[BN][BK];

    const int tid = threadIdx.x;
    const int wave = tid >> 6, lane = tid & 63;
    const int wm = (wave >> 1) * 64, wn = (wave & 1) * 64;
    const int lrow = lane & 15, quad = lane >> 4;
    const int bm = blockIdx.y * BM, bn = blockIdx.x * BN;
    const int z = blockIdx.z;

    const _Float16* pA = Ag + (size_t)z * az;
    const _Float16* pB = Bg + (size_t)z * bz;

    const int r0 = wave * 32 + (lane >> 2);
    const int kofs = (lane & 3) * 8;
    const size_t a0o = (size_t)(bm + r0) * lda + kofs;
    const size_t a1o = a0o + (size_t)16 * lda;
    const size_t b0o = (size_t)(bn + r0) * ldb + kofs;
    const size_t b1o = b0o + (size_t)16 * ldb;
    _Float16* lA0 = &sA[r0][kofs];
    _Float16* lA1 = &sA[r0 + 16][kofs];
    _Float16* lB0 = &sB[r0][kofs];
    _Float16* lB1 = &sB[r0 + 16][kofs];

    f32x4 acc[4][4];
#pragma unroll
    for (int i = 0; i < 4; ++i)
#pragma unroll
        for (int j = 0; j < 4; ++j) acc[i][j] = 0.0f;

    for (int k0 = 0; k0 < K; k0 += BK) {
        gl_lds16(pA + a0o + k0, lA0);
        gl_lds16(pA + a1o + k0, lA1);
        gl_lds16(pB + b0o + k0, lB0);
        gl_lds16(pB + b1o + k0, lB1);
        __syncthreads();

        half8_t a0[4], b0[4];
#pragma unroll
        for (int mt = 0; mt < 4; ++mt)
            a0[mt] = *(const half8_t*)&sA[wm + mt * 16 + lrow][quad * 8];
#pragma unroll
        for (int nt = 0; nt < 4; ++nt)
            b0[nt] = *(const half8_t*)&sB[wn + nt * 16 + lrow][quad * 8];
#pragma unroll
        for (int mt = 0; mt < 4; ++mt)
#pragma unroll
            for (int nt = 0; nt < 4; ++nt)
                acc[mt][nt] = __builtin_amdgcn_mfma_f32_16x16x32_f16(a0[mt], b0[nt], acc[mt][nt], 0, 0, 0);
        __syncthreads();
    }

#pragma unroll
    for (int mt = 0; mt < 4; ++mt)
#pragma unroll
        for (int nt = 0; nt < 4; ++nt) {
            int gm0 = bm + wm + mt * 16 + quad * 4;
            int gn = bn + wn + nt * 16 + lrow;
#pragma unroll
            for (int r = 0; r < 4; ++r)
                Cf[(size_t)z * cz + (size_t)(gm0 + r) * ldc + gn] = acc[mt][nt][r];
        }
}

// ---------------- softmax: fp32 scores row -> f16 P row, in place ----------------
__global__ __launch_bounds__(256) void softmax_kernel(float* __restrict__ S)
{
    float* row = S + (size_t)blockIdx.x * 2048;
    float4* r4 = (float4*)row;
    const int tid = threadIdx.x;
    const int wave = tid >> 6, lane = tid & 63;

    float4 a = r4[tid], b = r4[tid + 256];
    float m = fmaxf(fmaxf(fmaxf(a.x, a.y), fmaxf(a.z, a.w)),
                    fmaxf(fmaxf(b.x, b.y), fmaxf(b.z, b.w)));
#pragma unroll
    for (int o = 32; o; o >>= 1) m = fmaxf(m, __shfl_xor(m, o));
    __shared__ float redm[4];
    __shared__ float reds[4];
    if (lane == 0) redm[wave] = m;
    __syncthreads();
    m = fmaxf(fmaxf(redm[0], redm[1]), fmaxf(redm[2], redm[3]));

    a.x = __expf(a.x - m); a.y = __expf(a.y - m);
    a.z = __expf(a.z - m); a.w = __expf(a.w - m);
    b.x = __expf(b.x - m); b.y = __expf(b.y - m);
    b.z = __expf(b.z - m); b.w = __expf(b.w - m);

    float s = a.x + a.y + a.z + a.w + b.x + b.y + b.z + b.w;
#pragma unroll
    for (int o = 32; o; o >>= 1) s += __shfl_xor(s, o);
    if (lane == 0) reds[wave] = s;
    __syncthreads();
    s = reds[0] + reds[1] + reds[2] + reds[3];

    float inv = 1.0f / s;
    _Float16* o16 = (_Float16*)row;
    half4_t ha, hb;
    ha[0] = (_Float16)(a.x * inv); ha[1] = (_Float16)(a.y * inv);
    ha[2] = (_Float16)(a.z * inv); ha[3] = (_Float16)(a.w * inv);
    hb[0] = (_Float16)(b.x * inv); hb[1] = (_Float16)(b.y * inv);
    hb[2] = (_Float16)(b.z * inv); hb[3] = (_Float16)(b.w * inv);
    ((half4_t*)o16)[tid] = ha;
    ((half4_t*)o16)[tid + 256] = hb;
}

extern "C" void kernel_launch(void* const* d_in, const int* in_sizes, int n_in,
                              void* d_out, int out_size, void* d_ws, size_t ws_size,
                              hipStream_t stream)
{
    const float* x  = (const float*)d_in[0];
    const float* wq = (const float*)d_in[1];
    const float* wk = (const float*)d_in[2];
    const float* wv = (const float*)d_in[3];
    float* out = (float*)d_out;

    const int S = 2048, D = 1024;
    char* ws = (char*)d_ws;

    // ws layout (bytes); high-water 158 MB
    _Float16* xh   = (_Float16*)(ws);                  // 16 MB
    _Float16* xl   = (_Float16*)(ws + (16ull << 20));  // 16 MB
    _Float16* yh   = (_Float16*)(ws + (32ull << 20));  // 16 MB
    _Float16* yl   = (_Float16*)(ws + (48ull << 20));  // 16 MB
    _Float16* vT   = (_Float16*)(ws + (64ull << 20));  // 16 MB [4][1024][2048]
    _Float16* wqh  = (_Float16*)(ws + (80ull << 20));  // 2 MB (natural layout)
    _Float16* wql  = (_Float16*)(ws + (82ull << 20));  // 2 MB
    _Float16* wkh  = (_Float16*)(ws + (84ull << 20));  // 2 MB
    _Float16* wkl  = (_Float16*)(ws + (86ull << 20));  // 2 MB
    _Float16* wvTh = (_Float16*)(ws + (88ull << 20));  // 2 MB (transposed)
    _Float16* Mh   = (_Float16*)(ws + (90ull << 20));  // 2 MB  M' = Wk@Wq^T
    _Float16* Ml   = (_Float16*)(ws + (92ull << 20));  // 2 MB
    float*    sc   = (float*)(ws + (94ull << 20));     // 64 MB scores

    // 1) all conversions, flat grid
    conv_all_kernel<<<dim3(10496), dim3(256), 0, stream>>>(
        x, wq, wk, wv, xh, xl, wqh, wql, wkh, wkl, wvTh);

    // 2) M'[d'][d] = sum_e Wk[d',e]*Wq[d,e]  (split in, split out)
    gemm_split<false><<<dim3(D / BN, D / BM, 1), dim3(256), 0, stream>>>(
        wkh, wkl, 0, wqh, wql, 0, nullptr, 0, 0, Mh, Ml, 0, D, D, D, D);

    // 3) y-proj (split, coalesced epilogue) + v-proj (plain, coalesced vT)
    yv_kernel<<<dim3(D / BN, 8192 / BM, 2), dim3(256), 0, stream>>>(
        xh, xl, Mh, Ml, wvTh, yh, yl, vT);

    // 4) scores[b][s][t] = yh.xh + yh.xl + yl.xh over segmented K'=3072,
    //    256x256-tile 8-phase schedule, 256 blocks (1/CU), fp32 out
    scores_8ph<<<dim3(S / 256, S / 256, 4), dim3(512), 0, stream>>>(
        yh, yl, xh, xl, sc);

    // 5) softmax rows, f16 P written in place (row stride stays 8192 B)
    softmax_kernel<<<dim3(4 * S), dim3(256), 0, stream>>>(sc);

    // 6) out = P @ v: A=P f16 (lda=4096 f16 elems), B=vT f16, out fp32
    gemm_plain<<<dim3(D / BN, S / BM, 4), dim3(256), 0, stream>>>(
        (const _Float16*)sc, (size_t)S * 4096, vT, (size_t)D * S,
        out, (size_t)S * D, D, 4096, S, S);
}

// Round 2
// 409.279 us; speedup vs baseline: 1.0010x; 1.0010x over previous
//
#include <hip/hip_runtime.h>

// AttentionBlock: x[4,2048,1024] fp32; scores = x@(Wq@Wk^T)@x^T (NO scale);
// softmax; out = P@(x@Wv).
// M' = Wk@Wq^T -> y = x@M'^T replaces both q,k projections; scores = y@x^T.
// Split-f16 (hi+lo, 3-MFMA) for M', y, scores; plain f16 for v, PV.
// Round 11: scores_8ph v2 — r10's phase took 1587 cyc vs m201's 824 with
// identical per-phase work; VALUBusy 15% exposed ~60 rematerialized VALU
// per phase (swizzle offset + 64-bit address math on the lockstep critical
// path). Fixes: (a) K-loop hand-unrolled x2 so LDS slots are compile-time,
// (b) frag/staging byte-offsets precomputed and asm-pinned in VGPRs,
// (c) sched_barrier(0) dropped, (d) XCD-chunked block swizzle (A-panel
// locality; FETCH was 221MB vs 64MB unique).
// Confirmed dead ends: 128x256 tiles (r4/r5), 32x32x16 MFMA (r6: bank
// conflicts 3x), direct-to-VGPR lo loads (r7), BK=64 in old structure (r6).

typedef _Float16 half4_t __attribute__((ext_vector_type(4)));
typedef _Float16 half8_t __attribute__((ext_vector_type(8)));
typedef float f32x4 __attribute__((ext_vector_type(4)));

#define BM 128
#define BN 128
#define BK 32

__device__ __forceinline__ void gl_lds16(const _Float16* g, _Float16* l) {
    __builtin_amdgcn_global_load_lds(
        (const __attribute__((address_space(1))) unsigned int*)g,
        (__attribute__((address_space(3))) unsigned int*)l, 16, 0, 0);
}

// ---------------- merged conversion kernel (flat 1D grid) ----------------
__global__ __launch_bounds__(256) void conv_all_kernel(
    const float* __restrict__ x, const float* __restrict__ wq,
    const float* __restrict__ wk, const float* __restrict__ wv,
    _Float16* __restrict__ xh, _Float16* __restrict__ xl,
    _Float16* __restrict__ qh, _Float16* __restrict__ ql,
    _Float16* __restrict__ kh, _Float16* __restrict__ kl,
    _Float16* __restrict__ vTh)
{
    __shared__ float tle[64][65];
    const int bid = blockIdx.x;
    if (bid < 10240) {
        const float* in;
        _Float16 *hi, *lo;
        int i0;
        if (bid < 8192)      { in = x;  hi = xh; lo = xl; i0 = bid; }
        else if (bid < 9216) { in = wq; hi = qh; lo = ql; i0 = bid - 8192; }
        else                 { in = wk; hi = kh; lo = kl; i0 = bid - 9216; }
        int i = i0 * 256 + threadIdx.x;
        float4 v = ((const float4*)in)[i];
        float xs[4] = {v.x, v.y, v.z, v.w};
        half4_t h, l;
#pragma unroll
        for (int j = 0; j < 4; ++j) {
            _Float16 hh = (_Float16)xs[j];
            h[j] = hh;
            l[j] = (_Float16)(xs[j] - (float)hh);
        }
        ((half4_t*)hi)[i] = h;
        ((half4_t*)lo)[i] = l;
    } else {
        const int t = bid - 10240;
        const int tr = (t >> 4) * 64, tc = (t & 15) * 64;
        const int t16 = threadIdx.x & 15, tq = threadIdx.x >> 4;
#pragma unroll
        for (int j = 0; j < 4; ++j) {
            int lr = tq + j * 16;
            float4 v = *(const float4*)(wv + (size_t)(tr + lr) * 1024 + tc + t16 * 4);
            tle[lr][t16 * 4 + 0] = v.x;
            tle[lr][t16 * 4 + 1] = v.y;
            tle[lr][t16 * 4 + 2] = v.z;
            tle[lr][t16 * 4 + 3] = v.w;
        }
        __syncthreads();
#pragma unroll
        for (int j = 0; j < 4; ++j) {
            int orow = tq + j * 16;
            int oc = t16 * 4;
            half4_t h;
#pragma unroll
            for (int i = 0; i < 4; ++i) h[i] = (_Float16)tle[oc + i][orow];
            *(half4_t*)(vTh + (size_t)(tc + orow) * 1024 + tr + oc) = h;
        }
    }
}

// ---------------- split-f16 GEMM (3-MFMA, 16x16x32), 128x128 (M' only) ----------------
template <bool OUTF32>
__global__ __launch_bounds__(256) void gemm_split(
    const _Float16* __restrict__ Ah, const _Float16* __restrict__ Al, size_t az,
    const _Float16* __restrict__ Bh, const _Float16* __restrict__ Bl, size_t bz,
    float* __restrict__ Cf, size_t cz, int ldc,
    _Float16* __restrict__ Oh, _Float16* __restrict__ Ol, size_t oz, int ldo,
    int lda, int ldb, int K)
{
    __shared__ __align__(16) _Float16 sAh[BM][BK], sAl[BM][BK];
    __shared__ __align__(16) _Float16 sBh[BN][BK], sBl[BN][BK];

    const int tid = threadIdx.x;
    const int wave = tid >> 6, lane = tid & 63;
    const int wm = (wave >> 1) * 64, wn = (wave & 1) * 64;
    const int lrow = lane & 15, quad = lane >> 4;
    const int bm = blockIdx.y * BM, bn = blockIdx.x * BN;
    const int z = blockIdx.z;

    const _Float16* pAh = Ah + (size_t)z * az;
    const _Float16* pAl = Al + (size_t)z * az;
    const _Float16* pBh = Bh + (size_t)z * bz;
    const _Float16* pBl = Bl + (size_t)z * bz;

    const int r0 = wave * 32 + (lane >> 2);
    const int kofs = (lane & 3) * 8;
    const size_t a0o = (size_t)(bm + r0) * lda + kofs;
    const size_t a1o = a0o + (size_t)16 * lda;
    const size_t b0o = (size_t)(bn + r0) * ldb + kofs;
    const size_t b1o = b0o + (size_t)16 * ldb;
    _Float16* lA0 = &sAh[r0][kofs];
    _Float16* lA1 = &sAh[r0 + 16][kofs];
    _Float16* lAl0 = &sAl[r0][kofs];
    _Float16* lAl1 = &sAl[r0 + 16][kofs];
    _Float16* lB0 = &sBh[r0][kofs];
    _Float16* lB1 = &sBh[r0 + 16][kofs];
    _Float16* lBl0 = &sBl[r0][kofs];
    _Float16* lBl1 = &sBl[r0 + 16][kofs];

    f32x4 acc[4][4];
#pragma unroll
    for (int i = 0; i < 4; ++i)
#pragma unroll
        for (int j = 0; j < 4; ++j) acc[i][j] = 0.0f;

    for (int k0 = 0; k0 < K; k0 += BK) {
        gl_lds16(pAh + a0o + k0, lA0);
        gl_lds16(pAh + a1o + k0, lA1);
        gl_lds16(pAl + a0o + k0, lAl0);
        gl_lds16(pAl + a1o + k0, lAl1);
        gl_lds16(pBh + b0o + k0, lB0);
        gl_lds16(pBh + b1o + k0, lB1);
        gl_lds16(pBl + b0o + k0, lBl0);
        gl_lds16(pBl + b1o + k0, lBl1);
        __syncthreads();

        half8_t a0[4], a1[4], b0[4], b1[4];
#pragma unroll
        for (int mt = 0; mt < 4; ++mt) {
            a0[mt] = *(const half8_t*)&sAh[wm + mt * 16 + lrow][quad * 8];
            a1[mt] = *(const half8_t*)&sAl[wm + mt * 16 + lrow][quad * 8];
        }
#pragma unroll
        for (int nt = 0; nt < 4; ++nt) {
            b0[nt] = *(const half8_t*)&sBh[wn + nt * 16 + lrow][quad * 8];
            b1[nt] = *(const half8_t*)&sBl[wn + nt * 16 + lrow][quad * 8];
        }
#pragma unroll
        for (int mt = 0; mt < 4; ++mt)
#pragma unroll
            for (int nt = 0; nt < 4; ++nt) {
                acc[mt][nt] = __builtin_amdgcn_mfma_f32_16x16x32_f16(a0[mt], b0[nt], acc[mt][nt], 0, 0, 0);
                acc[mt][nt] = __builtin_amdgcn_mfma_f32_16x16x32_f16(a0[mt], b1[nt], acc[mt][nt], 0, 0, 0);
                acc[mt][nt] = __builtin_amdgcn_mfma_f32_16x16x32_f16(a1[mt], b0[nt], acc[mt][nt], 0, 0, 0);
            }
        __syncthreads();
    }

#pragma unroll
    for (int mt = 0; mt < 4; ++mt)
#pragma unroll
        for (int nt = 0; nt < 4; ++nt)
#pragma unroll
            for (int r = 0; r < 4; ++r) {
                int gm = bm + wm + mt * 16 + quad * 4 + r;
                int gn = bn + wn + nt * 16 + lrow;
                float v = acc[mt][nt][r];
                if (OUTF32) {
                    Cf[(size_t)z * cz + (size_t)gm * ldc + gn] = v;
                } else {
                    _Float16 h = (_Float16)v;
                    Oh[(size_t)z * oz + (size_t)gm * ldo + gn] = h;
                    Ol[(size_t)z * oz + (size_t)gm * ldo + gn] = (_Float16)(v - (float)h);
                }
            }
}

// ---------------- scores: 256x256-tile 8-phase GEMM, segmented K'=3072 ----------------
// v2: K-loop unrolled x2 (compile-time LDS slots), asm-pinned frag/stage
// offsets, no sched_barrier, XCD-chunked block swizzle. Schedule identical
// to r10: per phase {ds_read frags | stage 1 half-tile | barrier | setprio
// MFMA | barrier}; one vmcnt(4) per K-tile (2 half-tiles stay in flight).
#define NTILES 48  // 3072 / 64

__global__ __launch_bounds__(512, 2) void scores_8ph(
    const _Float16* __restrict__ yh, const _Float16* __restrict__ yl,
    const _Float16* __restrict__ xh, const _Float16* __restrict__ xl,
    float* __restrict__ Cf)
{
    __shared__ __align__(16) _Float16 sA[4][8192];  // 64KB
    __shared__ __align__(16) _Float16 sB[4][8192];  // 64KB

    const int tid = threadIdx.x;
    const int wave = tid >> 6, lane = tid & 63;
    const int wm = (wave >> 2) * 128;      // 2 wave-rows
    const int wn = (wave & 3) * 64;        // 4 wave-cols
    const int l15 = lane & 15, jq = lane >> 4;

    // XCD-chunked bijective swizzle: 256 blocks, XCD = flat%8 gets a
    // contiguous 32-block chunk of work -> A-panels localized to one XCD.
    const int flat = blockIdx.x + (blockIdx.y << 3) + (blockIdx.z << 6);
    const int work = ((flat & 7) << 5) + (flat >> 3);
    const int z = work >> 6;
    const int bm = ((work >> 3) & 7) * 256;
    const int bn = (work & 7) * 256;

    const _Float16* Ah = yh + ((size_t)z * 2048 + bm) * 1024;
    const _Float16* Al = yl + ((size_t)z * 2048 + bm) * 1024;
    const _Float16* Bh = xh + ((size_t)z * 2048 + bn) * 1024;
    const _Float16* Bl = xl + ((size_t)z * 2048 + bn) * 1024;

    // ---- precomputed, asm-pinned per-thread offsets (loop-invariant) ----
    // frag LDS byte offsets: chunk F = row*4 + (jq ^ ((row>>1)&3)), addr F*16
    int a_off[8], b_off[4];
#pragma unroll
    for (int h = 0; h < 2; ++h)
#pragma unroll
        for (int m = 0; m < 4; ++m) {
            int row = wm + h * 64 + m * 16 + l15;
            int F = row * 4 + (jq ^ ((row >> 1) & 3));
            a_off[h * 4 + m] = F * 16;
            asm volatile("" : "+v"(a_off[h * 4 + m]));
        }
#pragma unroll
    for (int n = 0; n < 4; ++n) {
        int row = wn + n * 16 + l15;
        int F = row * 4 + (jq ^ ((row >> 1) & 3));
        b_off[n] = F * 16;
        asm volatile("" : "+v"(b_off[n]));
    }
    // staging: thread fills chunks c0=tid (row tid>>2) and c1=512+tid
    // (row+128; swizzle j identical since 128 ≡ 0 mod 4 after >>1).
    int row0 = tid >> 2;
    int j0 = (tid & 3) ^ ((row0 >> 1) & 3);
    int g0 = row0 * 2048 + j0 * 16;   // global byte offset, i=0
    int g1 = g0 + 262144;             // +128 rows
    asm volatile("" : "+v"(g0), "+v"(g1));

    _Float16* SA0 = sA[0]; _Float16* SA1 = sA[1];
    _Float16* SA2 = sA[2]; _Float16* SA3 = sA[3];
    _Float16* SB0 = sB[0]; _Float16* SB1 = sB[1];
    _Float16* SB2 = sB[2]; _Float16* SB3 = sB[3];

    // stage one 16KB half-tile: uniform base p (SGPRs) + pinned lane offset
    auto STG = [&](const _Float16* p, _Float16* slot) {
        gl_lds16((const _Float16*)((const char*)p + g0), slot + tid * 8);
        gl_lds16((const _Float16*)((const char*)p + g1), slot + 4096 + tid * 8);
    };
    // segment panel bases (wave-uniform -> SALU): t<32 -> (Ah,*), else Al;
    // B plane: t in [16,32) -> Bl, else Bh.
    auto APAN = [&](int tt, int kh) {
        return (tt < 32 ? Ah : Al) + (tt & 15) * 64 + kh * 32;
    };
    auto BPAN = [&](int tt, int kh) {
        return ((tt >> 4) == 1 ? Bl : Bh) + (tt & 15) * 64 + kh * 32;
    };
    auto RDA = [&](const _Float16* slot, int half, half8_t* dst) {
#pragma unroll
        for (int m = 0; m < 4; ++m)
            dst[m] = *(const half8_t*)((const char*)slot + a_off[half * 4 + m]);
    };
    auto RDB = [&](const _Float16* slot, half8_t* dst) {
#pragma unroll
        for (int n = 0; n < 4; ++n)
            dst[n] = *(const half8_t*)((const char*)slot + b_off[n]);
    };

    f32x4 acc[8][4];
#pragma unroll
    for (int i = 0; i < 8; ++i)
#pragma unroll
        for (int j = 0; j < 4; ++j) acc[i][j] = 0.0f;

    auto MM = [&](half8_t* aa, half8_t* bb, int ah) {
#pragma unroll
        for (int m = 0; m < 4; ++m)
#pragma unroll
            for (int n = 0; n < 4; ++n)
                acc[ah * 4 + m][n] = __builtin_amdgcn_mfma_f32_16x16x32_f16(
                    aa[m], bb[n], acc[ah * 4 + m][n], 0, 0, 0);
    };

#define BAR   asm volatile("s_barrier" ::: "memory")
#define VMBAR asm volatile("s_waitcnt vmcnt(4)\n\ts_barrier" ::: "memory")
#define P1    __builtin_amdgcn_s_setprio(1)
#define P0    __builtin_amdgcn_s_setprio(0)

    // prologue: tile0 (both K-halves) + tile1 (K-half 0) = 6 half-tiles
    STG(APAN(0, 0), SA0); STG(BPAN(0, 0), SB0);
    STG(APAN(0, 1), SA1); STG(BPAN(0, 1), SB1);
    STG(APAN(1, 0), SA2); STG(BPAN(1, 0), SB2);
    VMBAR;   // tile0 resident; tile1-kh0 pair may stay in flight

    for (int t = 0; t < NTILES; t += 2) {
        const int u1 = t + 1;                                  // <= 47
        const int u2 = (t + 2 < NTILES) ? t + 2 : NTILES - 1;  // clamped src
        const int u3 = (t + 3 < NTILES) ? t + 3 : NTILES - 1;  // (dead slots)
        half8_t aa[4], bb[4];

        // ======== even tile t: read slots A0(kh0),A1(kh1),B0,B1 ========
        RDB(SB0, bb); RDA(SA0, 0, aa); STG(APAN(u1, 1), SA3);
        BAR; P1; MM(aa, bb, 0); P0; BAR;

        RDA(SA0, 1, aa); STG(BPAN(u1, 1), SB3);
        BAR; P1; MM(aa, bb, 1); P0; BAR;

        RDB(SB1, bb); RDA(SA1, 0, aa); STG(APAN(u2, 0), SA0);
        BAR; P1; MM(aa, bb, 0); P0; BAR;

        RDA(SA1, 1, aa); STG(BPAN(u2, 0), SB0);
        BAR; P1; MM(aa, bb, 1); P0; VMBAR;

        // ======== odd tile t+1: read slots A2(kh0),A3(kh1),B2,B3 ========
        RDB(SB2, bb); RDA(SA2, 0, aa); STG(APAN(u2, 1), SA1);
        BAR; P1; MM(aa, bb, 0); P0; BAR;

        RDA(SA2, 1, aa); STG(BPAN(u2, 1), SB1);
        BAR; P1; MM(aa, bb, 1); P0; BAR;

        RDB(SB3, bb); RDA(SA3, 0, aa); STG(APAN(u3, 0), SA2);
        BAR; P1; MM(aa, bb, 0); P0; BAR;

        RDA(SA3, 1, aa); STG(BPAN(u3, 0), SB2);
        BAR; P1; MM(aa, bb, 1); P0; VMBAR;
    }
    asm volatile("s_waitcnt vmcnt(0)" ::: "memory");

#undef BAR
#undef VMBAR
#undef P1
#undef P0

    // epilogue: fp32 C scatter (same layout as verified gemm_split)
    float* C = Cf + (size_t)z * 2048 * 2048;
#pragma unroll
    for (int mi = 0; mi < 8; ++mi)
#pragma unroll
        for (int ni = 0; ni < 4; ++ni) {
            int gm0 = bm + wm + mi * 16 + jq * 4;
            int gn = bn + wn + ni * 16 + l15;
#pragma unroll
            for (int r = 0; r < 4; ++r)
                C[(size_t)(gm0 + r) * 2048 + gn] = acc[mi][ni][r];
        }
}

// ---------------- merged y-proj (split) + v-proj (plain) kernel ----------------
__global__ __launch_bounds__(256) void yv_kernel(
    const _Float16* __restrict__ xh, const _Float16* __restrict__ xl,
    const _Float16* __restrict__ Mh, const _Float16* __restrict__ Ml,
    const _Float16* __restrict__ wvTh,
    _Float16* __restrict__ yh, _Float16* __restrict__ yl,
    _Float16* __restrict__ vT)
{
    __shared__ __align__(16) char buf[128 * 132 * 2];  // 33792 B

    const int tid = threadIdx.x;
    const int wave = tid >> 6, lane = tid & 63;
    const int wm = (wave >> 1) * 64, wn = (wave & 1) * 64;
    const int lrow = lane & 15, quad = lane >> 4;
    const int bm = blockIdx.y * BM, bn = blockIdx.x * BN;
    const bool vrole = (blockIdx.z != 0);

    const int r0 = wave * 32 + (lane >> 2);
    const int kofs = (lane & 3) * 8;
    const size_t a0o = (size_t)(bm + r0) * 1024 + kofs;
    const size_t a1o = a0o + (size_t)16 * 1024;
    const size_t b0o = (size_t)(bn + r0) * 1024 + kofs;
    const size_t b1o = b0o + (size_t)16 * 1024;

    f32x4 acc[4][4];
#pragma unroll
    for (int i = 0; i < 4; ++i)
#pragma unroll
        for (int j = 0; j < 4; ++j) acc[i][j] = 0.0f;

    _Float16* tle = (_Float16*)buf;

    if (!vrole) {
        _Float16* sAh = (_Float16*)buf;
        _Float16* sAl = (_Float16*)(buf + 8192);
        _Float16* sBh = (_Float16*)(buf + 16384);
        _Float16* sBl = (_Float16*)(buf + 24576);
        _Float16* lA0 = sAh + r0 * BK + kofs;
        _Float16* lA1 = sAh + (r0 + 16) * BK + kofs;
        _Float16* lAl0 = sAl + r0 * BK + kofs;
        _Float16* lAl1 = sAl + (r0 + 16) * BK + kofs;
        _Float16* lB0 = sBh + r0 * BK + kofs;
        _Float16* lB1 = sBh + (r0 + 16) * BK + kofs;
        _Float16* lBl0 = sBl + r0 * BK + kofs;
        _Float16* lBl1 = sBl + (r0 + 16) * BK + kofs;

        for (int k0 = 0; k0 < 1024; k0 += BK) {
            gl_lds16(xh + a0o + k0, lA0);
            gl_lds16(xh + a1o + k0, lA1);
            gl_lds16(xl + a0o + k0, lAl0);
            gl_lds16(xl + a1o + k0, lAl1);
            gl_lds16(Mh + b0o + k0, lB0);
            gl_lds16(Mh + b1o + k0, lB1);
            gl_lds16(Ml + b0o + k0, lBl0);
            gl_lds16(Ml + b1o + k0, lBl1);
            __syncthreads();

            half8_t a0[4], a1[4], b0[4], b1[4];
#pragma unroll
            for (int mt = 0; mt < 4; ++mt) {
                a0[mt] = *(const half8_t*)(sAh + (wm + mt * 16 + lrow) * BK + quad * 8);
                a1[mt] = *(const half8_t*)(sAl + (wm + mt * 16 + lrow) * BK + quad * 8);
            }
#pragma unroll
            for (int nt = 0; nt < 4; ++nt) {
                b0[nt] = *(const half8_t*)(sBh + (wn + nt * 16 + lrow) * BK + quad * 8);
                b1[nt] = *(const half8_t*)(sBl + (wn + nt * 16 + lrow) * BK + quad * 8);
            }
#pragma unroll
            for (int mt = 0; mt < 4; ++mt)
#pragma unroll
                for (int nt = 0; nt < 4; ++nt) {
                    acc[mt][nt] = __builtin_amdgcn_mfma_f32_16x16x32_f16(a0[mt], b0[nt], acc[mt][nt], 0, 0, 0);
                    acc[mt][nt] = __builtin_amdgcn_mfma_f32_16x16x32_f16(a0[mt], b1[nt], acc[mt][nt], 0, 0, 0);
                    acc[mt][nt] = __builtin_amdgcn_mfma_f32_16x16x32_f16(a1[mt], b0[nt], acc[mt][nt], 0, 0, 0);
                }
            __syncthreads();
        }

#pragma unroll
        for (int pass = 0; pass < 2; ++pass) {
            if (pass) __syncthreads();
#pragma unroll
            for (int mt = 0; mt < 4; ++mt)
#pragma unroll
                for (int nt = 0; nt < 4; ++nt) {
                    int rloc = wm + mt * 16 + quad * 4;
                    int cloc = wn + nt * 16 + lrow;
#pragma unroll
                    for (int r = 0; r < 4; ++r) {
                        float v = acc[mt][nt][r];
                        _Float16 h = (_Float16)v;
                        tle[(rloc + r) * 132 + cloc] =
                            pass == 0 ? h : (_Float16)(v - (float)h);
                    }
                }
            __syncthreads();
            _Float16* dst = pass == 0 ? yh : yl;
#pragma unroll
            for (int i = 0; i < 8; ++i) {
                int flat = i * 256 + tid;
                int rloc = flat >> 4, c = (flat & 15) * 8;
                half8_t o8;
#pragma unroll
                for (int j = 0; j < 8; ++j) o8[j] = tle[rloc * 132 + c + j];
                *(half8_t*)(dst + (size_t)(bm + rloc) * 1024 + bn + c) = o8;
            }
        }
    } else {
        _Float16* sA = (_Float16*)buf;
        _Float16* sB = (_Float16*)(buf + 8192);
        _Float16* lA0 = sA + r0 * BK + kofs;
        _Float16* lA1 = sA + (r0 + 16) * BK + kofs;
        _Float16* lB0 = sB + r0 * BK + kofs;
        _Float16* lB1 = sB + (r0 + 16) * BK + kofs;

        for (int k0 = 0; k0 < 1024; k0 += BK) {
            gl_lds16(xh + a0o + k0, lA0);
            gl_lds16(xh + a1o + k0, lA1);
            gl_lds16(wvTh + b0o + k0, lB0);
            gl_lds16(wvTh + b1o + k0, lB1);
            __syncthreads();

            half8_t a0[4], b0[4];
#pragma unroll
            for (int mt = 0; mt < 4; ++mt)
                a0[mt] = *(const half8_t*)(sA + (wm + mt * 16 + lrow) * BK + quad * 8);
#pragma unroll
            for (int nt = 0; nt < 4; ++nt)
                b0[nt] = *(const half8_t*)(sB + (wn + nt * 16 + lrow) * BK + quad * 8);
#pragma unroll
            for (int mt = 0; mt < 4; ++mt)
#pragma unroll
                for (int nt = 0; nt < 4; ++nt)
                    acc[mt][nt] = __builtin_amdgcn_mfma_f32_16x16x32_f16(a0[mt], b0[nt], acc[mt][nt], 0, 0, 0);
            __syncthreads();
        }

#pragma unroll
        for (int mt = 0; mt < 4; ++mt)
#pragma unroll
            for (int nt = 0; nt < 4; ++nt) {
                int t0 = wm + mt * 16 + quad * 4;
                int e_l = wn + nt * 16 + lrow;
                half4_t o;
#pragma unroll
                for (int r = 0; r < 4; ++r) o[r] = (_Float16)acc[mt][nt][r];
                *(half4_t*)(tle + e_l * 132 + t0) = o;
            }
        __syncthreads();
        const int b = bm >> 11, tb = bm & 2047;
#pragma unroll
        for (int i = 0; i < 8; ++i) {
            int flat = i * 256 + tid;
            int e_l = flat >> 4, c = (flat & 15) * 8;
            half8_t o8;
#pragma unroll
            for (int j = 0; j < 8; ++j) o8[j] = tle[e_l * 132 + c + j];
            *(half8_t*)(vT + ((size_t)b << 21) + (size_t)(bn + e_l) * 2048 + tb + c) = o8;
        }
    }
}

// ---------------- plain-f16 GEMM (16x16x32), 128x128, 256 thr (PV) ----------------
__global__ __launch_bounds__(256) void gemm_plain(
    const _Float16* __restrict__ Ag, size_t az,
    const _Float16* __restrict__ Bg, size_t bz,
    float* __restrict__ Cf, size_t cz, int ldc,
    int lda, int ldb, int K)
{
    __shared__ __align__(16) _Float16 sA[BM][BK], sB[BN][BK];

    const int tid = threadIdx.x;
    const int wave = tid >> 6, lane = tid & 63;
    const int wm = (wave >> 1) * 64, wn = (wave & 1) * 64;
    const int lrow = lane & 15, quad = lane >> 4;
    const int bm = blockIdx.y * BM, bn = blockIdx.x * BN;
    const int z = blockIdx.z;

    const _Float16* pA = Ag + (size_t)z * az;
    const _Float16* pB = Bg + (size_t)z * bz;

    const int r0 = wave * 32 + (lane >> 2);
    const int kofs = (lane & 3) * 8;
    const size_t a0o = (size_t)(bm + r0) * lda + kofs;
    const size_t a1o = a0o + (size_t)16 * lda;
    const size_t b0o = (size_t)(bn + r0) * ldb + kofs;
    const size_t b1o = b0o + (size_t)16 * ldb;
    _Float16* lA0 = &sA[r0][kofs];
    _Float16* lA1 = &sA[r0 + 16][kofs];
    _Float16* lB0 = &sB[r0][kofs];
    _Float16* lB1 = &sB[r0 + 16][kofs];

    f32x4 acc[4][4];
#pragma unroll
    for (int i = 0; i < 4; ++i)
#pragma unroll
        for (int j = 0; j < 4; ++j) acc[i][j] = 0.0f;

    for (int k0 = 0; k0 < K; k0 += BK) {
        gl_lds16(pA + a0o + k0, lA0);
        gl_lds16(pA + a1o + k0, lA1);
        gl_lds16(pB + b0o + k0, lB0);
        gl_lds16(pB + b1o + k0, lB1);
        __syncthreads();

        half8_t a0[4], b0[4];
#pragma unroll
        for (int mt = 0; mt < 4; ++mt)
            a0[mt] = *(const half8_t*)&sA[wm + mt * 16 + lrow][quad * 8];
#pragma unroll
        for (int nt = 0; nt < 4; ++nt)
            b0[nt] = *(const half8_t*)&sB[wn + nt * 16 + lrow][quad * 8];
#pragma unroll
        for (int mt = 0; mt < 4; ++mt)
#pragma unroll
            for (int nt = 0; nt < 4; ++nt)
                acc[mt][nt] = __builtin_amdgcn_mfma_f32_16x16x32_f16(a0[mt], b0[nt], acc[mt][nt], 0, 0, 0);
        __syncthreads();
    }

#pragma unroll
    for (int mt = 0; mt < 4; ++mt)
#pragma unroll
        for (int nt = 0; nt < 4; ++nt) {
            int gm0 = bm + wm + mt * 16 + quad * 4;
            int gn = bn + wn + nt * 16 + lrow;
#pragma unroll
            for (int r = 0; r < 4; ++r)
                Cf[(size_t)z * cz + (size_t)(gm0 + r) * ldc + gn] = acc[mt][nt][r];
        }
}

// ---------------- softmax: fp32 scores row -> f16 P row, in place ----------------
__global__ __launch_bounds__(256) void softmax_kernel(float* __restrict__ S)
{
    float* row = S + (size_t)blockIdx.x * 2048;
    float4* r4 = (float4*)row;
    const int tid = threadIdx.x;
    const int wave = tid >> 6, lane = tid & 63;

    float4 a = r4[tid], b = r4[tid + 256];
    float m = fmaxf(fmaxf(fmaxf(a.x, a.y), fmaxf(a.z, a.w)),
                    fmaxf(fmaxf(b.x, b.y), fmaxf(b.z, b.w)));
#pragma unroll
    for (int o = 32; o; o >>= 1) m = fmaxf(m, __shfl_xor(m, o));
    __shared__ float redm[4];
    __shared__ float reds[4];
    if (lane == 0) redm[wave] = m;
    __syncthreads();
    m = fmaxf(fmaxf(redm[0], redm[1]), fmaxf(redm[2], redm[3]));

    a.x = __expf(a.x - m); a.y = __expf(a.y - m);
    a.z = __expf(a.z - m); a.w = __expf(a.w - m);
    b.x = __expf(b.x - m); b.y = __expf(b.y - m);
    b.z = __expf(b.z - m); b.w = __expf(b.w - m);

    float s = a.x + a.y + a.z + a.w + b.x + b.y + b.z + b.w;
#pragma unroll
    for (int o = 32; o; o >>= 1) s += __shfl_xor(s, o);
    if (lane == 0) reds[wave] = s;
    __syncthreads();
    s = reds[0] + reds[1] + reds[2] + reds[3];

    float inv = 1.0f / s;
    _Float16* o16 = (_Float16*)row;
    half4_t ha, hb;
    ha[0] = (_Float16)(a.x * inv); ha[1] = (_Float16)(a.y * inv);
    ha[2] = (_Float16)(a.z * inv); ha[3] = (_Float16)(a.w * inv);
    hb[0] = (_Float16)(b.x * inv); hb[1] = (_Float16)(b.y * inv);
    hb[2] = (_Float16)(b.z * inv); hb[3] = (_Float16)(b.w * inv);
    ((half4_t*)o16)[tid] = ha;
    ((half4_t*)o16)[tid + 256] = hb;
}

extern "C" void kernel_launch(void* const* d_in, const int* in_sizes, int n_in,
                              void* d_out, int out_size, void* d_ws, size_t ws_size,
                              hipStream_t stream)
{
    const float* x  = (const float*)d_in[0];
    const float* wq = (const float*)d_in[1];
    const float* wk = (const float*)d_in[2];
    const float* wv = (const float*)d_in[3];
    float* out = (float*)d_out;

    const int S = 2048, D = 1024;
    char* ws = (char*)d_ws;

    // ws layout (bytes); high-water 158 MB
    _Float16* xh   = (_Float16*)(ws);                  // 16 MB
    _Float16* xl   = (_Float16*)(ws + (16ull << 20));  // 16 MB
    _Float16* yh   = (_Float16*)(ws + (32ull << 20));  // 16 MB
    _Float16* yl   = (_Float16*)(ws + (48ull << 20));  // 16 MB
    _Float16* vT   = (_Float16*)(ws + (64ull << 20));  // 16 MB [4][1024][2048]
    _Float16* wqh  = (_Float16*)(ws + (80ull << 20));  // 2 MB (natural layout)
    _Float16* wql  = (_Float16*)(ws + (82ull << 20));  // 2 MB
    _Float16* wkh  = (_Float16*)(ws + (84ull << 20));  // 2 MB
    _Float16* wkl  = (_Float16*)(ws + (86ull << 20));  // 2 MB
    _Float16* wvTh = (_Float16*)(ws + (88ull << 20));  // 2 MB (transposed)
    _Float16* Mh   = (_Float16*)(ws + (90ull << 20));  // 2 MB  M' = Wk@Wq^T
    _Float16* Ml   = (_Float16*)(ws + (92ull << 20));  // 2 MB
    float*    sc   = (float*)(ws + (94ull << 20));     // 64 MB scores

    // 1) all conversions, flat grid
    conv_all_kernel<<<dim3(10496), dim3(256), 0, stream>>>(
        x, wq, wk, wv, xh, xl, wqh, wql, wkh, wkl, wvTh);

    // 2) M'[d'][d] = sum_e Wk[d',e]*Wq[d,e]  (split in, split out)
    gemm_split<false><<<dim3(D / BN, D / BM, 1), dim3(256), 0, stream>>>(
        wkh, wkl, 0, wqh, wql, 0, nullptr, 0, 0, Mh, Ml, 0, D, D, D, D);

    // 3) y-proj (split, coalesced epilogue) + v-proj (plain, coalesced vT)
    yv_kernel<<<dim3(D / BN, 8192 / BM, 2), dim3(256), 0, stream>>>(
        xh, xl, Mh, Ml, wvTh, yh, yl, vT);

    // 4) scores over segmented K'=3072, 256x256-tile 8-phase, 256 blocks
    scores_8ph<<<dim3(S / 256, S / 256, 4), dim3(512), 0, stream>>>(
        yh, yl, xh, xl, sc);

    // 5) softmax rows, f16 P written in place (row stride stays 8192 B)
    softmax_kernel<<<dim3(4 * S), dim3(256), 0, stream>>>(sc);

    // 6) out = P @ v: A=P f16 (lda=4096 f16 elems), B=vT f16, out fp32
    gemm_plain<<<dim3(D / BN, S / BM, 4), dim3(256), 0, stream>>>(
        (const _Float16*)sc, (size_t)S * 4096, vT, (size_t)D * S,
        out, (size_t)S * D, D, 4096, S, S);
}

// Round 3
// 402.042 us; speedup vs baseline: 1.0190x; 1.0180x over previous
//
#include <hip/hip_runtime.h>

// AttentionBlock: x[4,2048,1024] fp32; scores = x@(Wq@Wk^T)@x^T (NO scale);
// softmax; out = P@(x@Wv).
// M' = Wk@Wq^T -> y = x@M'^T replaces both q,k projections; scores = y@x^T.
// Split-f16 (hi+lo, 3-MFMA) for M', y, scores; plain f16 for v, PV.
// Round 12: scores_8ph v3 — r10/r11 used asm barriers with "memory"
// clobbers; backend conservatively drains vmcnt(0)/lgkmcnt(0) before such
// asm, defeating the counted-vmcnt pipeline at every one of 8 barriers per
// K-tile (phase 1625 cyc vs m201's 824, invariant to VALU/fetch fixes).
// Fix: __builtin_amdgcn_s_barrier() + bare waitcnt asm (no clobber), per
// the verified m201 template. vmcnt(4) only at the per-tile checkpoint.
// Confirmed dead ends: 128x256 tiles (r4/r5), 32x32x16 MFMA (r6: bank
// conflicts 3x), direct-to-VGPR lo loads (r7), BK=64 in old structure (r6).

typedef _Float16 half4_t __attribute__((ext_vector_type(4)));
typedef _Float16 half8_t __attribute__((ext_vector_type(8)));
typedef float f32x4 __attribute__((ext_vector_type(4)));

#define BM 128
#define BN 128
#define BK 32

__device__ __forceinline__ void gl_lds16(const _Float16* g, _Float16* l) {
    __builtin_amdgcn_global_load_lds(
        (const __attribute__((address_space(1))) unsigned int*)g,
        (__attribute__((address_space(3))) unsigned int*)l, 16, 0, 0);
}

// ---------------- merged conversion kernel (flat 1D grid) ----------------
__global__ __launch_bounds__(256) void conv_all_kernel(
    const float* __restrict__ x, const float* __restrict__ wq,
    const float* __restrict__ wk, const float* __restrict__ wv,
    _Float16* __restrict__ xh, _Float16* __restrict__ xl,
    _Float16* __restrict__ qh, _Float16* __restrict__ ql,
    _Float16* __restrict__ kh, _Float16* __restrict__ kl,
    _Float16* __restrict__ vTh)
{
    __shared__ float tle[64][65];
    const int bid = blockIdx.x;
    if (bid < 10240) {
        const float* in;
        _Float16 *hi, *lo;
        int i0;
        if (bid < 8192)      { in = x;  hi = xh; lo = xl; i0 = bid; }
        else if (bid < 9216) { in = wq; hi = qh; lo = ql; i0 = bid - 8192; }
        else                 { in = wk; hi = kh; lo = kl; i0 = bid - 9216; }
        int i = i0 * 256 + threadIdx.x;
        float4 v = ((const float4*)in)[i];
        float xs[4] = {v.x, v.y, v.z, v.w};
        half4_t h, l;
#pragma unroll
        for (int j = 0; j < 4; ++j) {
            _Float16 hh = (_Float16)xs[j];
            h[j] = hh;
            l[j] = (_Float16)(xs[j] - (float)hh);
        }
        ((half4_t*)hi)[i] = h;
        ((half4_t*)lo)[i] = l;
    } else {
        const int t = bid - 10240;
        const int tr = (t >> 4) * 64, tc = (t & 15) * 64;
        const int t16 = threadIdx.x & 15, tq = threadIdx.x >> 4;
#pragma unroll
        for (int j = 0; j < 4; ++j) {
            int lr = tq + j * 16;
            float4 v = *(const float4*)(wv + (size_t)(tr + lr) * 1024 + tc + t16 * 4);
            tle[lr][t16 * 4 + 0] = v.x;
            tle[lr][t16 * 4 + 1] = v.y;
            tle[lr][t16 * 4 + 2] = v.z;
            tle[lr][t16 * 4 + 3] = v.w;
        }
        __syncthreads();
#pragma unroll
        for (int j = 0; j < 4; ++j) {
            int orow = tq + j * 16;
            int oc = t16 * 4;
            half4_t h;
#pragma unroll
            for (int i = 0; i < 4; ++i) h[i] = (_Float16)tle[oc + i][orow];
            *(half4_t*)(vTh + (size_t)(tc + orow) * 1024 + tr + oc) = h;
        }
    }
}

// ---------------- split-f16 GEMM (3-MFMA, 16x16x32), 128x128 (M' only) ----------------
template <bool OUTF32>
__global__ __launch_bounds__(256) void gemm_split(
    const _Float16* __restrict__ Ah, const _Float16* __restrict__ Al, size_t az,
    const _Float16* __restrict__ Bh, const _Float16* __restrict__ Bl, size_t bz,
    float* __restrict__ Cf, size_t cz, int ldc,
    _Float16* __restrict__ Oh, _Float16* __restrict__ Ol, size_t oz, int ldo,
    int lda, int ldb, int K)
{
    __shared__ __align__(16) _Float16 sAh[BM][BK], sAl[BM][BK];
    __shared__ __align__(16) _Float16 sBh[BN][BK], sBl[BN][BK];

    const int tid = threadIdx.x;
    const int wave = tid >> 6, lane = tid & 63;
    const int wm = (wave >> 1) * 64, wn = (wave & 1) * 64;
    const int lrow = lane & 15, quad = lane >> 4;
    const int bm = blockIdx.y * BM, bn = blockIdx.x * BN;
    const int z = blockIdx.z;

    const _Float16* pAh = Ah + (size_t)z * az;
    const _Float16* pAl = Al + (size_t)z * az;
    const _Float16* pBh = Bh + (size_t)z * bz;
    const _Float16* pBl = Bl + (size_t)z * bz;

    const int r0 = wave * 32 + (lane >> 2);
    const int kofs = (lane & 3) * 8;
    const size_t a0o = (size_t)(bm + r0) * lda + kofs;
    const size_t a1o = a0o + (size_t)16 * lda;
    const size_t b0o = (size_t)(bn + r0) * ldb + kofs;
    const size_t b1o = b0o + (size_t)16 * ldb;
    _Float16* lA0 = &sAh[r0][kofs];
    _Float16* lA1 = &sAh[r0 + 16][kofs];
    _Float16* lAl0 = &sAl[r0][kofs];
    _Float16* lAl1 = &sAl[r0 + 16][kofs];
    _Float16* lB0 = &sBh[r0][kofs];
    _Float16* lB1 = &sBh[r0 + 16][kofs];
    _Float16* lBl0 = &sBl[r0][kofs];
    _Float16* lBl1 = &sBl[r0 + 16][kofs];

    f32x4 acc[4][4];
#pragma unroll
    for (int i = 0; i < 4; ++i)
#pragma unroll
        for (int j = 0; j < 4; ++j) acc[i][j] = 0.0f;

    for (int k0 = 0; k0 < K; k0 += BK) {
        gl_lds16(pAh + a0o + k0, lA0);
        gl_lds16(pAh + a1o + k0, lA1);
        gl_lds16(pAl + a0o + k0, lAl0);
        gl_lds16(pAl + a1o + k0, lAl1);
        gl_lds16(pBh + b0o + k0, lB0);
        gl_lds16(pBh + b1o + k0, lB1);
        gl_lds16(pBl + b0o + k0, lBl0);
        gl_lds16(pBl + b1o + k0, lBl1);
        __syncthreads();

        half8_t a0[4], a1[4], b0[4], b1[4];
#pragma unroll
        for (int mt = 0; mt < 4; ++mt) {
            a0[mt] = *(const half8_t*)&sAh[wm + mt * 16 + lrow][quad * 8];
            a1[mt] = *(const half8_t*)&sAl[wm + mt * 16 + lrow][quad * 8];
        }
#pragma unroll
        for (int nt = 0; nt < 4; ++nt) {
            b0[nt] = *(const half8_t*)&sBh[wn + nt * 16 + lrow][quad * 8];
            b1[nt] = *(const half8_t*)&sBl[wn + nt * 16 + lrow][quad * 8];
        }
#pragma unroll
        for (int mt = 0; mt < 4; ++mt)
#pragma unroll
            for (int nt = 0; nt < 4; ++nt) {
                acc[mt][nt] = __builtin_amdgcn_mfma_f32_16x16x32_f16(a0[mt], b0[nt], acc[mt][nt], 0, 0, 0);
                acc[mt][nt] = __builtin_amdgcn_mfma_f32_16x16x32_f16(a0[mt], b1[nt], acc[mt][nt], 0, 0, 0);
                acc[mt][nt] = __builtin_amdgcn_mfma_f32_16x16x32_f16(a1[mt], b0[nt], acc[mt][nt], 0, 0, 0);
            }
        __syncthreads();
    }

#pragma unroll
    for (int mt = 0; mt < 4; ++mt)
#pragma unroll
        for (int nt = 0; nt < 4; ++nt)
#pragma unroll
            for (int r = 0; r < 4; ++r) {
                int gm = bm + wm + mt * 16 + quad * 4 + r;
                int gn = bn + wn + nt * 16 + lrow;
                float v = acc[mt][nt][r];
                if (OUTF32) {
                    Cf[(size_t)z * cz + (size_t)gm * ldc + gn] = v;
                } else {
                    _Float16 h = (_Float16)v;
                    Oh[(size_t)z * oz + (size_t)gm * ldo + gn] = h;
                    Ol[(size_t)z * oz + (size_t)gm * ldo + gn] = (_Float16)(v - (float)h);
                }
            }
}

// ---------------- scores: 256x256-tile 8-phase GEMM, segmented K'=3072 ----------------
// v3: builtin barriers + bare (clobber-free) waitcnt asm, per m201
// template. Per phase {ds_read frags | stage 1 half-tile | barrier |
// lgkmcnt(0) | setprio MFMA | barrier}; one bare vmcnt(4) per K-tile
// (2 half-tiles = 4 loads stay in flight across barriers; never 0).
#define NTILES 48  // 3072 / 64

__global__ __launch_bounds__(512, 2) void scores_8ph(
    const _Float16* __restrict__ yh, const _Float16* __restrict__ yl,
    const _Float16* __restrict__ xh, const _Float16* __restrict__ xl,
    float* __restrict__ Cf)
{
    __shared__ __align__(16) _Float16 sA[4][8192];  // 64KB
    __shared__ __align__(16) _Float16 sB[4][8192];  // 64KB

    const int tid = threadIdx.x;
    const int wave = tid >> 6, lane = tid & 63;
    const int wm = (wave >> 2) * 128;      // 2 wave-rows
    const int wn = (wave & 3) * 64;        // 4 wave-cols
    const int l15 = lane & 15, jq = lane >> 4;

    // XCD-chunked bijective swizzle: 256 blocks, XCD = flat%8 gets a
    // contiguous 32-block chunk of work -> A-panels localized to one XCD.
    const int flat = blockIdx.x + (blockIdx.y << 3) + (blockIdx.z << 6);
    const int work = ((flat & 7) << 5) + (flat >> 3);
    const int z = work >> 6;
    const int bm = ((work >> 3) & 7) * 256;
    const int bn = (work & 7) * 256;

    const _Float16* Ah = yh + ((size_t)z * 2048 + bm) * 1024;
    const _Float16* Al = yl + ((size_t)z * 2048 + bm) * 1024;
    const _Float16* Bh = xh + ((size_t)z * 2048 + bn) * 1024;
    const _Float16* Bl = xl + ((size_t)z * 2048 + bn) * 1024;

    // ---- precomputed, asm-pinned per-thread offsets (loop-invariant) ----
    // frag LDS byte offsets: chunk F = row*4 + (jq ^ ((row>>1)&3)), addr F*16
    int a_off[8], b_off[4];
#pragma unroll
    for (int h = 0; h < 2; ++h)
#pragma unroll
        for (int m = 0; m < 4; ++m) {
            int row = wm + h * 64 + m * 16 + l15;
            int F = row * 4 + (jq ^ ((row >> 1) & 3));
            a_off[h * 4 + m] = F * 16;
            asm volatile("" : "+v"(a_off[h * 4 + m]));
        }
#pragma unroll
    for (int n = 0; n < 4; ++n) {
        int row = wn + n * 16 + l15;
        int F = row * 4 + (jq ^ ((row >> 1) & 3));
        b_off[n] = F * 16;
        asm volatile("" : "+v"(b_off[n]));
    }
    // staging: thread fills chunks c0=tid (row tid>>2) and c1=512+tid
    // (row+128; swizzle j identical since 128 ≡ 0 mod 4 after >>1).
    int row0 = tid >> 2;
    int j0 = (tid & 3) ^ ((row0 >> 1) & 3);
    int g0 = row0 * 2048 + j0 * 16;   // global byte offset, i=0
    int g1 = g0 + 262144;             // +128 rows
    asm volatile("" : "+v"(g0), "+v"(g1));

    _Float16* SA0 = sA[0]; _Float16* SA1 = sA[1];
    _Float16* SA2 = sA[2]; _Float16* SA3 = sA[3];
    _Float16* SB0 = sB[0]; _Float16* SB1 = sB[1];
    _Float16* SB2 = sB[2]; _Float16* SB3 = sB[3];

    // stage one 16KB half-tile: uniform base p (SGPRs) + pinned lane offset
    auto STG = [&](const _Float16* p, _Float16* slot) {
        gl_lds16((const _Float16*)((const char*)p + g0), slot + tid * 8);
        gl_lds16((const _Float16*)((const char*)p + g1), slot + 4096 + tid * 8);
    };
    // segment panel bases (wave-uniform -> SALU): t<32 -> (Ah,*), else Al;
    // B plane: t in [16,32) -> Bl, else Bh.
    auto APAN = [&](int tt, int kh) {
        return (tt < 32 ? Ah : Al) + (tt & 15) * 64 + kh * 32;
    };
    auto BPAN = [&](int tt, int kh) {
        return ((tt >> 4) == 1 ? Bl : Bh) + (tt & 15) * 64 + kh * 32;
    };
    auto RDA = [&](const _Float16* slot, int half, half8_t* dst) {
#pragma unroll
        for (int m = 0; m < 4; ++m)
            dst[m] = *(const half8_t*)((const char*)slot + a_off[half * 4 + m]);
    };
    auto RDB = [&](const _Float16* slot, half8_t* dst) {
#pragma unroll
        for (int n = 0; n < 4; ++n)
            dst[n] = *(const half8_t*)((const char*)slot + b_off[n]);
    };

    f32x4 acc[8][4];
#pragma unroll
    for (int i = 0; i < 8; ++i)
#pragma unroll
        for (int j = 0; j < 4; ++j) acc[i][j] = 0.0f;

    auto MM = [&](half8_t* aa, half8_t* bb, int ah) {
#pragma unroll
        for (int m = 0; m < 4; ++m)
#pragma unroll
            for (int n = 0; n < 4; ++n)
                acc[ah * 4 + m][n] = __builtin_amdgcn_mfma_f32_16x16x32_f16(
                    aa[m], bb[n], acc[ah * 4 + m][n], 0, 0, 0);
    };

    // template-faithful barrier/waitcnt forms: builtin barrier, bare asm
    // waitcnt (NO "memory" clobber -> no conservative vmcnt(0) drain).
#define BARRIER __builtin_amdgcn_s_barrier()
#define LGKM0   asm volatile("s_waitcnt lgkmcnt(0)")
#define VM4     asm volatile("s_waitcnt vmcnt(4)")
#define P1      __builtin_amdgcn_s_setprio(1)
#define P0      __builtin_amdgcn_s_setprio(0)

    // prologue: tile0 (both K-halves) + tile1 (K-half 0) = 6 half-tiles
    STG(APAN(0, 0), SA0); STG(BPAN(0, 0), SB0);
    STG(APAN(0, 1), SA1); STG(BPAN(0, 1), SB1);
    STG(APAN(1, 0), SA2); STG(BPAN(1, 0), SB2);
    VM4;      // tile0 resident; tile1-kh0 pair may stay in flight
    BARRIER;

    for (int t = 0; t < NTILES; t += 2) {
        const int u1 = t + 1;                                  // <= 47
        const int u2 = (t + 2 < NTILES) ? t + 2 : NTILES - 1;  // clamped src
        const int u3 = (t + 3 < NTILES) ? t + 3 : NTILES - 1;  // (dead slots)
        half8_t aa[4], bb[4];

        // ======== even tile t: read slots A0(kh0),A1(kh1),B0,B1 ========
        RDB(SB0, bb); RDA(SA0, 0, aa); STG(APAN(u1, 1), SA3);
        BARRIER; LGKM0; P1; MM(aa, bb, 0); P0; BARRIER;

        RDA(SA0, 1, aa); STG(BPAN(u1, 1), SB3);
        BARRIER; LGKM0; P1; MM(aa, bb, 1); P0; BARRIER;

        RDB(SB1, bb); RDA(SA1, 0, aa); STG(APAN(u2, 0), SA0);
        BARRIER; LGKM0; P1; MM(aa, bb, 0); P0; BARRIER;

        RDA(SA1, 1, aa); STG(BPAN(u2, 0), SB0);
        BARRIER; LGKM0; P1; MM(aa, bb, 1); P0; VM4; BARRIER;

        // ======== odd tile t+1: read slots A2(kh0),A3(kh1),B2,B3 ========
        RDB(SB2, bb); RDA(SA2, 0, aa); STG(APAN(u2, 1), SA1);
        BARRIER; LGKM0; P1; MM(aa, bb, 0); P0; BARRIER;

        RDA(SA2, 1, aa); STG(BPAN(u2, 1), SB1);
        BARRIER; LGKM0; P1; MM(aa, bb, 1); P0; BARRIER;

        RDB(SB3, bb); RDA(SA3, 0, aa); STG(APAN(u3, 0), SA2);
        BARRIER; LGKM0; P1; MM(aa, bb, 0); P0; BARRIER;

        RDA(SA3, 1, aa); STG(BPAN(u3, 0), SB2);
        BARRIER; LGKM0; P1; MM(aa, bb, 1); P0; VM4; BARRIER;
    }
    asm volatile("s_waitcnt vmcnt(0)");

#undef BARRIER
#undef LGKM0
#undef VM4
#undef P1
#undef P0

    // epilogue: fp32 C scatter (same layout as verified gemm_split)
    float* C = Cf + (size_t)z * 2048 * 2048;
#pragma unroll
    for (int mi = 0; mi < 8; ++mi)
#pragma unroll
        for (int ni = 0; ni < 4; ++ni) {
            int gm0 = bm + wm + mi * 16 + jq * 4;
            int gn = bn + wn + ni * 16 + l15;
#pragma unroll
            for (int r = 0; r < 4; ++r)
                C[(size_t)(gm0 + r) * 2048 + gn] = acc[mi][ni][r];
        }
}

// ---------------- merged y-proj (split) + v-proj (plain) kernel ----------------
__global__ __launch_bounds__(256) void yv_kernel(
    const _Float16* __restrict__ xh, const _Float16* __restrict__ xl,
    const _Float16* __restrict__ Mh, const _Float16* __restrict__ Ml,
    const _Float16* __restrict__ wvTh,
    _Float16* __restrict__ yh, _Float16* __restrict__ yl,
    _Float16* __restrict__ vT)
{
    __shared__ __align__(16) char buf[128 * 132 * 2];  // 33792 B

    const int tid = threadIdx.x;
    const int wave = tid >> 6, lane = tid & 63;
    const int wm = (wave >> 1) * 64, wn = (wave & 1) * 64;
    const int lrow = lane & 15, quad = lane >> 4;
    const int bm = blockIdx.y * BM, bn = blockIdx.x * BN;
    const bool vrole = (blockIdx.z != 0);

    const int r0 = wave * 32 + (lane >> 2);
    const int kofs = (lane & 3) * 8;
    const size_t a0o = (size_t)(bm + r0) * 1024 + kofs;
    const size_t a1o = a0o + (size_t)16 * 1024;
    const size_t b0o = (size_t)(bn + r0) * 1024 + kofs;
    const size_t b1o = b0o + (size_t)16 * 1024;

    f32x4 acc[4][4];
#pragma unroll
    for (int i = 0; i < 4; ++i)
#pragma unroll
        for (int j = 0; j < 4; ++j) acc[i][j] = 0.0f;

    _Float16* tle = (_Float16*)buf;

    if (!vrole) {
        _Float16* sAh = (_Float16*)buf;
        _Float16* sAl = (_Float16*)(buf + 8192);
        _Float16* sBh = (_Float16*)(buf + 16384);
        _Float16* sBl = (_Float16*)(buf + 24576);
        _Float16* lA0 = sAh + r0 * BK + kofs;
        _Float16* lA1 = sAh + (r0 + 16) * BK + kofs;
        _Float16* lAl0 = sAl + r0 * BK + kofs;
        _Float16* lAl1 = sAl + (r0 + 16) * BK + kofs;
        _Float16* lB0 = sBh + r0 * BK + kofs;
        _Float16* lB1 = sBh + (r0 + 16) * BK + kofs;
        _Float16* lBl0 = sBl + r0 * BK + kofs;
        _Float16* lBl1 = sBl + (r0 + 16) * BK + kofs;

        for (int k0 = 0; k0 < 1024; k0 += BK) {
            gl_lds16(xh + a0o + k0, lA0);
            gl_lds16(xh + a1o + k0, lA1);
            gl_lds16(xl + a0o + k0, lAl0);
            gl_lds16(xl + a1o + k0, lAl1);
            gl_lds16(Mh + b0o + k0, lB0);
            gl_lds16(Mh + b1o + k0, lB1);
            gl_lds16(Ml + b0o + k0, lBl0);
            gl_lds16(Ml + b1o + k0, lBl1);
            __syncthreads();

            half8_t a0[4], a1[4], b0[4], b1[4];
#pragma unroll
            for (int mt = 0; mt < 4; ++mt) {
                a0[mt] = *(const half8_t*)(sAh + (wm + mt * 16 + lrow) * BK + quad * 8);
                a1[mt] = *(const half8_t*)(sAl + (wm + mt * 16 + lrow) * BK + quad * 8);
            }
#pragma unroll
            for (int nt = 0; nt < 4; ++nt) {
                b0[nt] = *(const half8_t*)(sBh + (wn + nt * 16 + lrow) * BK + quad * 8);
                b1[nt] = *(const half8_t*)(sBl + (wn + nt * 16 + lrow) * BK + quad * 8);
            }
#pragma unroll
            for (int mt = 0; mt < 4; ++mt)
#pragma unroll
                for (int nt = 0; nt < 4; ++nt) {
                    acc[mt][nt] = __builtin_amdgcn_mfma_f32_16x16x32_f16(a0[mt], b0[nt], acc[mt][nt], 0, 0, 0);
                    acc[mt][nt] = __builtin_amdgcn_mfma_f32_16x16x32_f16(a0[mt], b1[nt], acc[mt][nt], 0, 0, 0);
                    acc[mt][nt] = __builtin_amdgcn_mfma_f32_16x16x32_f16(a1[mt], b0[nt], acc[mt][nt], 0, 0, 0);
                }
            __syncthreads();
        }

#pragma unroll
        for (int pass = 0; pass < 2; ++pass) {
            if (pass) __syncthreads();
#pragma unroll
            for (int mt = 0; mt < 4; ++mt)
#pragma unroll
                for (int nt = 0; nt < 4; ++nt) {
                    int rloc = wm + mt * 16 + quad * 4;
                    int cloc = wn + nt * 16 + lrow;
#pragma unroll
                    for (int r = 0; r < 4; ++r) {
                        float v = acc[mt][nt][r];
                        _Float16 h = (_Float16)v;
                        tle[(rloc + r) * 132 + cloc] =
                            pass == 0 ? h : (_Float16)(v - (float)h);
                    }
                }
            __syncthreads();
            _Float16* dst = pass == 0 ? yh : yl;
#pragma unroll
            for (int i = 0; i < 8; ++i) {
                int flat = i * 256 + tid;
                int rloc = flat >> 4, c = (flat & 15) * 8;
                half8_t o8;
#pragma unroll
                for (int j = 0; j < 8; ++j) o8[j] = tle[rloc * 132 + c + j];
                *(half8_t*)(dst + (size_t)(bm + rloc) * 1024 + bn + c) = o8;
            }
        }
    } else {
        _Float16* sA = (_Float16*)buf;
        _Float16* sB = (_Float16*)(buf + 8192);
        _Float16* lA0 = sA + r0 * BK + kofs;
        _Float16* lA1 = sA + (r0 + 16) * BK + kofs;
        _Float16* lB0 = sB + r0 * BK + kofs;
        _Float16* lB1 = sB + (r0 + 16) * BK + kofs;

        for (int k0 = 0; k0 < 1024; k0 += BK) {
            gl_lds16(xh + a0o + k0, lA0);
            gl_lds16(xh + a1o + k0, lA1);
            gl_lds16(wvTh + b0o + k0, lB0);
            gl_lds16(wvTh + b1o + k0, lB1);
            __syncthreads();

            half8_t a0[4], b0[4];
#pragma unroll
            for (int mt = 0; mt < 4; ++mt)
                a0[mt] = *(const half8_t*)(sA + (wm + mt * 16 + lrow) * BK + quad * 8);
#pragma unroll
            for (int nt = 0; nt < 4; ++nt)
                b0[nt] = *(const half8_t*)(sB + (wn + nt * 16 + lrow) * BK + quad * 8);
#pragma unroll
            for (int mt = 0; mt < 4; ++mt)
#pragma unroll
                for (int nt = 0; nt < 4; ++nt)
                    acc[mt][nt] = __builtin_amdgcn_mfma_f32_16x16x32_f16(a0[mt], b0[nt], acc[mt][nt], 0, 0, 0);
            __syncthreads();
        }

#pragma unroll
        for (int mt = 0; mt < 4; ++mt)
#pragma unroll
            for (int nt = 0; nt < 4; ++nt) {
                int t0 = wm + mt * 16 + quad * 4;
                int e_l = wn + nt * 16 + lrow;
                half4_t o;
#pragma unroll
                for (int r = 0; r < 4; ++r) o[r] = (_Float16)acc[mt][nt][r];
                *(half4_t*)(tle + e_l * 132 + t0) = o;
            }
        __syncthreads();
        const int b = bm >> 11, tb = bm & 2047;
#pragma unroll
        for (int i = 0; i < 8; ++i) {
            int flat = i * 256 + tid;
            int e_l = flat >> 4, c = (flat & 15) * 8;
            half8_t o8;
#pragma unroll
            for (int j = 0; j < 8; ++j) o8[j] = tle[e_l * 132 + c + j];
            *(half8_t*)(vT + ((size_t)b << 21) + (size_t)(bn + e_l) * 2048 + tb + c) = o8;
        }
    }
}

// ---------------- plain-f16 GEMM (16x16x32), 128x128, 256 thr (PV) ----------------
__global__ __launch_bounds__(256) void gemm_plain(
    const _Float16* __restrict__ Ag, size_t az,
    const _Float16* __restrict__ Bg, size_t bz,
    float* __restrict__ Cf, size_t cz, int ldc,
    int lda, int ldb, int K)
{
    __shared__ __align__(16) _Float16 sA[BM][BK], sB[BN][BK];

    const int tid = threadIdx.x;
    const int wave = tid >> 6, lane = tid & 63;
    const int wm = (wave >> 1) * 64, wn = (wave & 1) * 64;
    const int lrow = lane & 15, quad = lane >> 4;
    const int bm = blockIdx.y * BM, bn = blockIdx.x * BN;
    const int z = blockIdx.z;

    const _Float16* pA = Ag + (size_t)z * az;
    const _Float16* pB = Bg + (size_t)z * bz;

    const int r0 = wave * 32 + (lane >> 2);
    const int kofs = (lane & 3) * 8;
    const size_t a0o = (size_t)(bm + r0) * lda + kofs;
    const size_t a1o = a0o + (size_t)16 * lda;
    const size_t b0o = (size_t)(bn + r0) * ldb + kofs;
    const size_t b1o = b0o + (size_t)16 * ldb;
    _Float16* lA0 = &sA[r0][kofs];
    _Float16* lA1 = &sA[r0 + 16][kofs];
    _Float16* lB0 = &sB[r0][kofs];
    _Float16* lB1 = &sB[r0 + 16][kofs];

    f32x4 acc[4][4];
#pragma unroll
    for (int i = 0; i < 4; ++i)
#pragma unroll
        for (int j = 0; j < 4; ++j) acc[i][j] = 0.0f;

    for (int k0 = 0; k0 < K; k0 += BK) {
        gl_lds16(pA + a0o + k0, lA0);
        gl_lds16(pA + a1o + k0, lA1);
        gl_lds16(pB + b0o + k0, lB0);
        gl_lds16(pB + b1o + k0, lB1);
        __syncthreads();

        half8_t a0[4], b0[4];
#pragma unroll
        for (int mt = 0; mt < 4; ++mt)
            a0[mt] = *(const half8_t*)&sA[wm + mt * 16 + lrow][quad * 8];
#pragma unroll
        for (int nt = 0; nt < 4; ++nt)
            b0[nt] = *(const half8_t*)&sB[wn + nt * 16 + lrow][quad * 8];
#pragma unroll
        for (int mt = 0; mt < 4; ++mt)
#pragma unroll
            for (int nt = 0; nt < 4; ++nt)
                acc[mt][nt] = __builtin_amdgcn_mfma_f32_16x16x32_f16(a0[mt], b0[nt], acc[mt][nt], 0, 0, 0);
        __syncthreads();
    }

#pragma unroll
    for (int mt = 0; mt < 4; ++mt)
#pragma unroll
        for (int nt = 0; nt < 4; ++nt) {
            int gm0 = bm + wm + mt * 16 + quad * 4;
            int gn = bn + wn + nt * 16 + lrow;
#pragma unroll
            for (int r = 0; r < 4; ++r)
                Cf[(size_t)z * cz + (size_t)(gm0 + r) * ldc + gn] = acc[mt][nt][r];
        }
}

// ---------------- softmax: fp32 scores row -> f16 P row, in place ----------------
__global__ __launch_bounds__(256) void softmax_kernel(float* __restrict__ S)
{
    float* row = S + (size_t)blockIdx.x * 2048;
    float4* r4 = (float4*)row;
    const int tid = threadIdx.x;
    const int wave = tid >> 6, lane = tid & 63;

    float4 a = r4[tid], b = r4[tid + 256];
    float m = fmaxf(fmaxf(fmaxf(a.x, a.y), fmaxf(a.z, a.w)),
                    fmaxf(fmaxf(b.x, b.y), fmaxf(b.z, b.w)));
#pragma unroll
    for (int o = 32; o; o >>= 1) m = fmaxf(m, __shfl_xor(m, o));
    __shared__ float redm[4];
    __shared__ float reds[4];
    if (lane == 0) redm[wave] = m;
    __syncthreads();
    m = fmaxf(fmaxf(redm[0], redm[1]), fmaxf(redm[2], redm[3]));

    a.x = __expf(a.x - m); a.y = __expf(a.y - m);
    a.z = __expf(a.z - m); a.w = __expf(a.w - m);
    b.x = __expf(b.x - m); b.y = __expf(b.y - m);
    b.z = __expf(b.z - m); b.w = __expf(b.w - m);

    float s = a.x + a.y + a.z + a.w + b.x + b.y + b.z + b.w;
#pragma unroll
    for (int o = 32; o; o >>= 1) s += __shfl_xor(s, o);
    if (lane == 0) reds[wave] = s;
    __syncthreads();
    s = reds[0] + reds[1] + reds[2] + reds[3];

    float inv = 1.0f / s;
    _Float16* o16 = (_Float16*)row;
    half4_t ha, hb;
    ha[0] = (_Float16)(a.x * inv); ha[1] = (_Float16)(a.y * inv);
    ha[2] = (_Float16)(a.z * inv); ha[3] = (_Float16)(a.w * inv);
    hb[0] = (_Float16)(b.x * inv); hb[1] = (_Float16)(b.y * inv);
    hb[2] = (_Float16)(b.z * inv); hb[3] = (_Float16)(b.w * inv);
    ((half4_t*)o16)[tid] = ha;
    ((half4_t*)o16)[tid + 256] = hb;
}

extern "C" void kernel_launch(void* const* d_in, const int* in_sizes, int n_in,
                              void* d_out, int out_size, void* d_ws, size_t ws_size,
                              hipStream_t stream)
{
    const float* x  = (const float*)d_in[0];
    const float* wq = (const float*)d_in[1];
    const float* wk = (const float*)d_in[2];
    const float* wv = (const float*)d_in[3];
    float* out = (float*)d_out;

    const int S = 2048, D = 1024;
    char* ws = (char*)d_ws;

    // ws layout (bytes); high-water 158 MB
    _Float16* xh   = (_Float16*)(ws);                  // 16 MB
    _Float16* xl   = (_Float16*)(ws + (16ull << 20));  // 16 MB
    _Float16* yh   = (_Float16*)(ws + (32ull << 20));  // 16 MB
    _Float16* yl   = (_Float16*)(ws + (48ull << 20));  // 16 MB
    _Float16* vT   = (_Float16*)(ws + (64ull << 20));  // 16 MB [4][1024][2048]
    _Float16* wqh  = (_Float16*)(ws + (80ull << 20));  // 2 MB (natural layout)
    _Float16* wql  = (_Float16*)(ws + (82ull << 20));  // 2 MB
    _Float16* wkh  = (_Float16*)(ws + (84ull << 20));  // 2 MB
    _Float16* wkl  = (_Float16*)(ws + (86ull << 20));  // 2 MB
    _Float16* wvTh = (_Float16*)(ws + (88ull << 20));  // 2 MB (transposed)
    _Float16* Mh   = (_Float16*)(ws + (90ull << 20));  // 2 MB  M' = Wk@Wq^T
    _Float16* Ml   = (_Float16*)(ws + (92ull << 20));  // 2 MB
    float*    sc   = (float*)(ws + (94ull << 20));     // 64 MB scores

    // 1) all conversions, flat grid
    conv_all_kernel<<<dim3(10496), dim3(256), 0, stream>>>(
        x, wq, wk, wv, xh, xl, wqh, wql, wkh, wkl, wvTh);

    // 2) M'[d'][d] = sum_e Wk[d',e]*Wq[d,e]  (split in, split out)
    gemm_split<false><<<dim3(D / BN, D / BM, 1), dim3(256), 0, stream>>>(
        wkh, wkl, 0, wqh, wql, 0, nullptr, 0, 0, Mh, Ml, 0, D, D, D, D);

    // 3) y-proj (split, coalesced epilogue) + v-proj (plain, coalesced vT)
    yv_kernel<<<dim3(D / BN, 8192 / BM, 2), dim3(256), 0, stream>>>(
        xh, xl, Mh, Ml, wvTh, yh, yl, vT);

    // 4) scores over segmented K'=3072, 256x256-tile 8-phase, 256 blocks
    scores_8ph<<<dim3(S / 256, S / 256, 4), dim3(512), 0, stream>>>(
        yh, yl, xh, xl, sc);

    // 5) softmax rows, f16 P written in place (row stride stays 8192 B)
    softmax_kernel<<<dim3(4 * S), dim3(256), 0, stream>>>(sc);

    // 6) out = P @ v: A=P f16 (lda=4096 f16 elems), B=vT f16, out fp32
    gemm_plain<<<dim3(D / BN, S / BM, 4), dim3(256), 0, stream>>>(
        (const _Float16*)sc, (size_t)S * 4096, vT, (size_t)D * S,
        out, (size_t)S * D, D, 4096, S, S);
}

// Round 4
// 393.835 us; speedup vs baseline: 1.0402x; 1.0208x over previous
//
#include <hip/hip_runtime.h>

// AttentionBlock: x[4,2048,1024] fp32; scores = x@(Wq@Wk^T)@x^T (NO scale);
// softmax; out = P@(x@Wv).
// M' = Wk@Wq^T -> y = x@M'^T replaces both q,k projections; scores = y@x^T.
// Split-f16 (hi+lo, 3-MFMA) for M', y, scores; plain f16 for v, PV.
// Round 13: scores_8ph v4 — reg-staged (T14). Theory: global_load_lds
// (LDS-DMA) forces a conservative vmcnt drain at every s_barrier (compiler
// can't track DMA writes per-address), exposing ~800cy HBM latency per
// phase (1600 cyc/phase vs m201's 824, invariant to r10-r12 fixes; r9's
// 2-barrier loop with 4x fewer drains = faster). Fix: global->VGPR loads
// issued 2 phases ahead + ds_write_b128 in-phase (HipKittens' own choice).
// Plain VMEM at barriers needs no drain; compiler emits precise vmcnt
// before each ds_write's reg use. Manual vmcnt checkpoints removed.
// Confirmed dead ends: 128x256 tiles (r4/r5), 32x32x16 MFMA (r6: bank
// conflicts 3x), direct-to-VGPR lo loads (r7), BK=64 in old structure (r6).

typedef _Float16 half4_t __attribute__((ext_vector_type(4)));
typedef _Float16 half8_t __attribute__((ext_vector_type(8)));
typedef float f32x4 __attribute__((ext_vector_type(4)));

#define BM 128
#define BN 128
#define BK 32

__device__ __forceinline__ void gl_lds16(const _Float16* g, _Float16* l) {
    __builtin_amdgcn_global_load_lds(
        (const __attribute__((address_space(1))) unsigned int*)g,
        (__attribute__((address_space(3))) unsigned int*)l, 16, 0, 0);
}

// ---------------- merged conversion kernel (flat 1D grid) ----------------
__global__ __launch_bounds__(256) void conv_all_kernel(
    const float* __restrict__ x, const float* __restrict__ wq,
    const float* __restrict__ wk, const float* __restrict__ wv,
    _Float16* __restrict__ xh, _Float16* __restrict__ xl,
    _Float16* __restrict__ qh, _Float16* __restrict__ ql,
    _Float16* __restrict__ kh, _Float16* __restrict__ kl,
    _Float16* __restrict__ vTh)
{
    __shared__ float tle[64][65];
    const int bid = blockIdx.x;
    if (bid < 10240) {
        const float* in;
        _Float16 *hi, *lo;
        int i0;
        if (bid < 8192)      { in = x;  hi = xh; lo = xl; i0 = bid; }
        else if (bid < 9216) { in = wq; hi = qh; lo = ql; i0 = bid - 8192; }
        else                 { in = wk; hi = kh; lo = kl; i0 = bid - 9216; }
        int i = i0 * 256 + threadIdx.x;
        float4 v = ((const float4*)in)[i];
        float xs[4] = {v.x, v.y, v.z, v.w};
        half4_t h, l;
#pragma unroll
        for (int j = 0; j < 4; ++j) {
            _Float16 hh = (_Float16)xs[j];
            h[j] = hh;
            l[j] = (_Float16)(xs[j] - (float)hh);
        }
        ((half4_t*)hi)[i] = h;
        ((half4_t*)lo)[i] = l;
    } else {
        const int t = bid - 10240;
        const int tr = (t >> 4) * 64, tc = (t & 15) * 64;
        const int t16 = threadIdx.x & 15, tq = threadIdx.x >> 4;
#pragma unroll
        for (int j = 0; j < 4; ++j) {
            int lr = tq + j * 16;
            float4 v = *(const float4*)(wv + (size_t)(tr + lr) * 1024 + tc + t16 * 4);
            tle[lr][t16 * 4 + 0] = v.x;
            tle[lr][t16 * 4 + 1] = v.y;
            tle[lr][t16 * 4 + 2] = v.z;
            tle[lr][t16 * 4 + 3] = v.w;
        }
        __syncthreads();
#pragma unroll
        for (int j = 0; j < 4; ++j) {
            int orow = tq + j * 16;
            int oc = t16 * 4;
            half4_t h;
#pragma unroll
            for (int i = 0; i < 4; ++i) h[i] = (_Float16)tle[oc + i][orow];
            *(half4_t*)(vTh + (size_t)(tc + orow) * 1024 + tr + oc) = h;
        }
    }
}

// ---------------- split-f16 GEMM (3-MFMA, 16x16x32), 128x128 (M' only) ----------------
template <bool OUTF32>
__global__ __launch_bounds__(256) void gemm_split(
    const _Float16* __restrict__ Ah, const _Float16* __restrict__ Al, size_t az,
    const _Float16* __restrict__ Bh, const _Float16* __restrict__ Bl, size_t bz,
    float* __restrict__ Cf, size_t cz, int ldc,
    _Float16* __restrict__ Oh, _Float16* __restrict__ Ol, size_t oz, int ldo,
    int lda, int ldb, int K)
{
    __shared__ __align__(16) _Float16 sAh[BM][BK], sAl[BM][BK];
    __shared__ __align__(16) _Float16 sBh[BN][BK], sBl[BN][BK];

    const int tid = threadIdx.x;
    const int wave = tid >> 6, lane = tid & 63;
    const int wm = (wave >> 1) * 64, wn = (wave & 1) * 64;
    const int lrow = lane & 15, quad = lane >> 4;
    const int bm = blockIdx.y * BM, bn = blockIdx.x * BN;
    const int z = blockIdx.z;

    const _Float16* pAh = Ah + (size_t)z * az;
    const _Float16* pAl = Al + (size_t)z * az;
    const _Float16* pBh = Bh + (size_t)z * bz;
    const _Float16* pBl = Bl + (size_t)z * bz;

    const int r0 = wave * 32 + (lane >> 2);
    const int kofs = (lane & 3) * 8;
    const size_t a0o = (size_t)(bm + r0) * lda + kofs;
    const size_t a1o = a0o + (size_t)16 * lda;
    const size_t b0o = (size_t)(bn + r0) * ldb + kofs;
    const size_t b1o = b0o + (size_t)16 * ldb;
    _Float16* lA0 = &sAh[r0][kofs];
    _Float16* lA1 = &sAh[r0 + 16][kofs];
    _Float16* lAl0 = &sAl[r0][kofs];
    _Float16* lAl1 = &sAl[r0 + 16][kofs];
    _Float16* lB0 = &sBh[r0][kofs];
    _Float16* lB1 = &sBh[r0 + 16][kofs];
    _Float16* lBl0 = &sBl[r0][kofs];
    _Float16* lBl1 = &sBl[r0 + 16][kofs];

    f32x4 acc[4][4];
#pragma unroll
    for (int i = 0; i < 4; ++i)
#pragma unroll
        for (int j = 0; j < 4; ++j) acc[i][j] = 0.0f;

    for (int k0 = 0; k0 < K; k0 += BK) {
        gl_lds16(pAh + a0o + k0, lA0);
        gl_lds16(pAh + a1o + k0, lA1);
        gl_lds16(pAl + a0o + k0, lAl0);
        gl_lds16(pAl + a1o + k0, lAl1);
        gl_lds16(pBh + b0o + k0, lB0);
        gl_lds16(pBh + b1o + k0, lB1);
        gl_lds16(pBl + b0o + k0, lBl0);
        gl_lds16(pBl + b1o + k0, lBl1);
        __syncthreads();

        half8_t a0[4], a1[4], b0[4], b1[4];
#pragma unroll
        for (int mt = 0; mt < 4; ++mt) {
            a0[mt] = *(const half8_t*)&sAh[wm + mt * 16 + lrow][quad * 8];
            a1[mt] = *(const half8_t*)&sAl[wm + mt * 16 + lrow][quad * 8];
        }
#pragma unroll
        for (int nt = 0; nt < 4; ++nt) {
            b0[nt] = *(const half8_t*)&sBh[wn + nt * 16 + lrow][quad * 8];
            b1[nt] = *(const half8_t*)&sBl[wn + nt * 16 + lrow][quad * 8];
        }
#pragma unroll
        for (int mt = 0; mt < 4; ++mt)
#pragma unroll
            for (int nt = 0; nt < 4; ++nt) {
                acc[mt][nt] = __builtin_amdgcn_mfma_f32_16x16x32_f16(a0[mt], b0[nt], acc[mt][nt], 0, 0, 0);
                acc[mt][nt] = __builtin_amdgcn_mfma_f32_16x16x32_f16(a0[mt], b1[nt], acc[mt][nt], 0, 0, 0);
                acc[mt][nt] = __builtin_amdgcn_mfma_f32_16x16x32_f16(a1[mt], b0[nt], acc[mt][nt], 0, 0, 0);
            }
        __syncthreads();
    }

#pragma unroll
    for (int mt = 0; mt < 4; ++mt)
#pragma unroll
        for (int nt = 0; nt < 4; ++nt)
#pragma unroll
            for (int r = 0; r < 4; ++r) {
                int gm = bm + wm + mt * 16 + quad * 4 + r;
                int gn = bn + wn + nt * 16 + lrow;
                float v = acc[mt][nt][r];
                if (OUTF32) {
                    Cf[(size_t)z * cz + (size_t)gm * ldc + gn] = v;
                } else {
                    _Float16 h = (_Float16)v;
                    Oh[(size_t)z * oz + (size_t)gm * ldo + gn] = h;
                    Ol[(size_t)z * oz + (size_t)gm * ldo + gn] = (_Float16)(v - (float)h);
                }
            }
}

// ---------------- scores: 256x256-tile 8-phase GEMM, segmented K'=3072 ----------------
// v4: reg-staged staging (T14). Per phase {ds_read frags | ds_write one
// half-tile from regs (loaded 2 phases ago) | issue global_load_dwordx4 x2
// for the half-tile written 2 phases later | barrier | lgkmcnt(0) |
// setprio MFMA | barrier}. No global_load_lds, no manual vmcnt: compiler
// inserts precise vmcnt before each ds_write's register use.
#define NTILES 48  // 3072 / 64

__global__ __launch_bounds__(512, 2) void scores_8ph(
    const _Float16* __restrict__ yh, const _Float16* __restrict__ yl,
    const _Float16* __restrict__ xh, const _Float16* __restrict__ xl,
    float* __restrict__ Cf)
{
    __shared__ __align__(16) _Float16 sA[4][8192];  // 64KB
    __shared__ __align__(16) _Float16 sB[4][8192];  // 64KB

    const int tid = threadIdx.x;
    const int wave = tid >> 6, lane = tid & 63;
    const int wm = (wave >> 2) * 128;      // 2 wave-rows
    const int wn = (wave & 3) * 64;        // 4 wave-cols
    const int l15 = lane & 15, jq = lane >> 4;

    // XCD-chunked bijective swizzle: 256 blocks, XCD = flat%8 gets a
    // contiguous 32-block chunk of work -> A-panels localized to one XCD.
    const int flat = blockIdx.x + (blockIdx.y << 3) + (blockIdx.z << 6);
    const int work = ((flat & 7) << 5) + (flat >> 3);
    const int z = work >> 6;
    const int bm = ((work >> 3) & 7) * 256;
    const int bn = (work & 7) * 256;

    const _Float16* Ah = yh + ((size_t)z * 2048 + bm) * 1024;
    const _Float16* Al = yl + ((size_t)z * 2048 + bm) * 1024;
    const _Float16* Bh = xh + ((size_t)z * 2048 + bn) * 1024;
    const _Float16* Bl = xl + ((size_t)z * 2048 + bn) * 1024;

    // ---- precomputed, asm-pinned per-thread offsets (loop-invariant) ----
    // frag LDS byte offsets: chunk F = row*4 + (jq ^ ((row>>1)&3)), addr F*16
    int a_off[8], b_off[4];
#pragma unroll
    for (int h = 0; h < 2; ++h)
#pragma unroll
        for (int m = 0; m < 4; ++m) {
            int row = wm + h * 64 + m * 16 + l15;
            int F = row * 4 + (jq ^ ((row >> 1) & 3));
            a_off[h * 4 + m] = F * 16;
            asm volatile("" : "+v"(a_off[h * 4 + m]));
        }
#pragma unroll
    for (int n = 0; n < 4; ++n) {
        int row = wn + n * 16 + l15;
        int F = row * 4 + (jq ^ ((row >> 1) & 3));
        b_off[n] = F * 16;
        asm volatile("" : "+v"(b_off[n]));
    }
    // staging: thread covers chunks c0=tid (row tid>>2) and c1=512+tid
    // (row+128; swizzle j identical since 128 ≡ 0 mod 4 after >>1).
    int row0 = tid >> 2;
    int j0 = (tid & 3) ^ ((row0 >> 1) & 3);
    int g0 = row0 * 2048 + j0 * 16;   // global byte offset, chunk c0
    int g1 = g0 + 262144;             // +128 rows, chunk c1
    int wb0 = tid * 16;               // LDS byte offset for chunk c0
    int wb1 = 8192 + tid * 16;        // chunk c1
    asm volatile("" : "+v"(g0), "+v"(g1), "+v"(wb0), "+v"(wb1));

    _Float16* SA0 = sA[0]; _Float16* SA1 = sA[1];
    _Float16* SA2 = sA[2]; _Float16* SA3 = sA[3];
    _Float16* SB0 = sB[0]; _Float16* SB1 = sB[1];
    _Float16* SB2 = sB[2]; _Float16* SB3 = sB[3];

    // in-flight half-tile register sets (2 loads x 16B each)
    f32x4 rAk0[2], rBk0[2], rAk1[2], rBk1[2];

    auto ISSUE = [&](const _Float16* p, f32x4* r) {
        r[0] = *(const f32x4*)((const char*)p + g0);
        r[1] = *(const f32x4*)((const char*)p + g1);
    };
    auto WRITE = [&](const f32x4* r, _Float16* slot) {
        *(f32x4*)((char*)slot + wb0) = r[0];
        *(f32x4*)((char*)slot + wb1) = r[1];
    };
    // segment panel bases (wave-uniform -> SALU): t<32 -> (Ah,*), else Al;
    // B plane: t in [16,32) -> Bl, else Bh.
    auto APAN = [&](int tt, int kh) {
        return (tt < 32 ? Ah : Al) + (tt & 15) * 64 + kh * 32;
    };
    auto BPAN = [&](int tt, int kh) {
        return ((tt >> 4) == 1 ? Bl : Bh) + (tt & 15) * 64 + kh * 32;
    };
    auto RDA = [&](const _Float16* slot, int half, half8_t* dst) {
#pragma unroll
        for (int m = 0; m < 4; ++m)
            dst[m] = *(const half8_t*)((const char*)slot + a_off[half * 4 + m]);
    };
    auto RDB = [&](const _Float16* slot, half8_t* dst) {
#pragma unroll
        for (int n = 0; n < 4; ++n)
            dst[n] = *(const half8_t*)((const char*)slot + b_off[n]);
    };

    f32x4 acc[8][4];
#pragma unroll
    for (int i = 0; i < 8; ++i)
#pragma unroll
        for (int j = 0; j < 4; ++j) acc[i][j] = 0.0f;

    auto MM = [&](half8_t* aa, half8_t* bb, int ah) {
#pragma unroll
        for (int m = 0; m < 4; ++m)
#pragma unroll
            for (int n = 0; n < 4; ++n)
                acc[ah * 4 + m][n] = __builtin_amdgcn_mfma_f32_16x16x32_f16(
                    aa[m], bb[n], acc[ah * 4 + m][n], 0, 0, 0);
    };

#define BARRIER __builtin_amdgcn_s_barrier()
#define LGKM0   asm volatile("s_waitcnt lgkmcnt(0)")
#define P1      __builtin_amdgcn_s_setprio(1)
#define P0      __builtin_amdgcn_s_setprio(0)

    // prologue: tiles 0 (both halves) + 1 (kh0) to LDS; tile1-kh1 left
    // pending in rAk1/rBk1 (written at Eq0/Eq1 of the first iteration).
    ISSUE(APAN(0, 0), rAk0); ISSUE(BPAN(0, 0), rBk0);
    ISSUE(APAN(0, 1), rAk1); ISSUE(BPAN(0, 1), rBk1);
    WRITE(rAk0, SA0); WRITE(rBk0, SB0);
    WRITE(rAk1, SA1); WRITE(rBk1, SB1);
    ISSUE(APAN(1, 0), rAk0); ISSUE(BPAN(1, 0), rBk0);
    WRITE(rAk0, SA2); WRITE(rBk0, SB2);
    ISSUE(APAN(1, 1), rAk1); ISSUE(BPAN(1, 1), rBk1);
    LGKM0;
    BARRIER;

    for (int t = 0; t < NTILES; t += 2) {
        const int u2 = (t + 2 < NTILES) ? t + 2 : NTILES - 1;  // clamped src
        const int u3 = (t + 3 < NTILES) ? t + 3 : NTILES - 1;  // (dead slots)
        half8_t aa[4], bb[4];

        // ======== even tile t: slots A0/B0 (kh0), A1/B1 (kh1) ========
        // Eq0: write SA3<-(t+1,k1,A); issue (t+2,k0,A)
        RDB(SB0, bb); RDA(SA0, 0, aa);
        WRITE(rAk1, SA3); ISSUE(APAN(u2, 0), rAk0);
        BARRIER; LGKM0; P1; MM(aa, bb, 0); P0; BARRIER;

        // Eq1: write SB3<-(t+1,k1,B); issue (t+2,k0,B)
        RDA(SA0, 1, aa);
        WRITE(rBk1, SB3); ISSUE(BPAN(u2, 0), rBk0);
        BARRIER; LGKM0; P1; MM(aa, bb, 1); P0; BARRIER;

        // Eq2: write SA0<-(t+2,k0,A); issue (t+2,k1,A)
        RDB(SB1, bb); RDA(SA1, 0, aa);
        WRITE(rAk0, SA0); ISSUE(APAN(u2, 1), rAk1);
        BARRIER; LGKM0; P1; MM(aa, bb, 0); P0; BARRIER;

        // Eq3: write SB0<-(t+2,k0,B); issue (t+2,k1,B)
        RDA(SA1, 1, aa);
        WRITE(rBk0, SB0); ISSUE(BPAN(u2, 1), rBk1);
        BARRIER; LGKM0; P1; MM(aa, bb, 1); P0; BARRIER;

        // ======== odd tile t+1: slots A2/B2 (kh0), A3/B3 (kh1) ========
        // Oq0: write SA1<-(t+2,k1,A); issue (t+3,k0,A)
        RDB(SB2, bb); RDA(SA2, 0, aa);
        WRITE(rAk1, SA1); ISSUE(APAN(u3, 0), rAk0);
        BARRIER; LGKM0; P1; MM(aa, bb, 0); P0; BARRIER;

        // Oq1: write SB1<-(t+2,k1,B); issue (t+3,k0,B)
        RDA(SA2, 1, aa);
        WRITE(rBk1, SB1); ISSUE(BPAN(u3, 0), rBk0);
        BARRIER; LGKM0; P1; MM(aa, bb, 1); P0; BARRIER;

        // Oq2: write SA2<-(t+3,k0,A); issue (t+3,k1,A)
        RDB(SB3, bb); RDA(SA3, 0, aa);
        WRITE(rAk0, SA2); ISSUE(APAN(u3, 1), rAk1);
        BARRIER; LGKM0; P1; MM(aa, bb, 0); P0; BARRIER;

        // Oq3: write SB2<-(t+3,k0,B); issue (t+3,k1,B)
        RDA(SA3, 1, aa);
        WRITE(rBk0, SB2); ISSUE(BPAN(u3, 1), rBk1);
        BARRIER; LGKM0; P1; MM(aa, bb, 1); P0; BARRIER;
    }

#undef BARRIER
#undef LGKM0
#undef P1
#undef P0

    // epilogue: fp32 C scatter (same layout as verified gemm_split)
    float* C = Cf + (size_t)z * 2048 * 2048;
#pragma unroll
    for (int mi = 0; mi < 8; ++mi)
#pragma unroll
        for (int ni = 0; ni < 4; ++ni) {
            int gm0 = bm + wm + mi * 16 + jq * 4;
            int gn = bn + wn + ni * 16 + l15;
#pragma unroll
            for (int r = 0; r < 4; ++r)
                C[(size_t)(gm0 + r) * 2048 + gn] = acc[mi][ni][r];
        }
}

// ---------------- merged y-proj (split) + v-proj (plain) kernel ----------------
__global__ __launch_bounds__(256) void yv_kernel(
    const _Float16* __restrict__ xh, const _Float16* __restrict__ xl,
    const _Float16* __restrict__ Mh, const _Float16* __restrict__ Ml,
    const _Float16* __restrict__ wvTh,
    _Float16* __restrict__ yh, _Float16* __restrict__ yl,
    _Float16* __restrict__ vT)
{
    __shared__ __align__(16) char buf[128 * 132 * 2];  // 33792 B

    const int tid = threadIdx.x;
    const int wave = tid >> 6, lane = tid & 63;
    const int wm = (wave >> 1) * 64, wn = (wave & 1) * 64;
    const int lrow = lane & 15, quad = lane >> 4;
    const int bm = blockIdx.y * BM, bn = blockIdx.x * BN;
    const bool vrole = (blockIdx.z != 0);

    const int r0 = wave * 32 + (lane >> 2);
    const int kofs = (lane & 3) * 8;
    const size_t a0o = (size_t)(bm + r0) * 1024 + kofs;
    const size_t a1o = a0o + (size_t)16 * 1024;
    const size_t b0o = (size_t)(bn + r0) * 1024 + kofs;
    const size_t b1o = b0o + (size_t)16 * 1024;

    f32x4 acc[4][4];
#pragma unroll
    for (int i = 0; i < 4; ++i)
#pragma unroll
        for (int j = 0; j < 4; ++j) acc[i][j] = 0.0f;

    _Float16* tle = (_Float16*)buf;

    if (!vrole) {
        _Float16* sAh = (_Float16*)buf;
        _Float16* sAl = (_Float16*)(buf + 8192);
        _Float16* sBh = (_Float16*)(buf + 16384);
        _Float16* sBl = (_Float16*)(buf + 24576);
        _Float16* lA0 = sAh + r0 * BK + kofs;
        _Float16* lA1 = sAh + (r0 + 16) * BK + kofs;
        _Float16* lAl0 = sAl + r0 * BK + kofs;
        _Float16* lAl1 = sAl + (r0 + 16) * BK + kofs;
        _Float16* lB0 = sBh + r0 * BK + kofs;
        _Float16* lB1 = sBh + (r0 + 16) * BK + kofs;
        _Float16* lBl0 = sBl + r0 * BK + kofs;
        _Float16* lBl1 = sBl + (r0 + 16) * BK + kofs;

        for (int k0 = 0; k0 < 1024; k0 += BK) {
            gl_lds16(xh + a0o + k0, lA0);
            gl_lds16(xh + a1o + k0, lA1);
            gl_lds16(xl + a0o + k0, lAl0);
            gl_lds16(xl + a1o + k0, lAl1);
            gl_lds16(Mh + b0o + k0, lB0);
            gl_lds16(Mh + b1o + k0, lB1);
            gl_lds16(Ml + b0o + k0, lBl0);
            gl_lds16(Ml + b1o + k0, lBl1);
            __syncthreads();

            half8_t a0[4], a1[4], b0[4], b1[4];
#pragma unroll
            for (int mt = 0; mt < 4; ++mt) {
                a0[mt] = *(const half8_t*)(sAh + (wm + mt * 16 + lrow) * BK + quad * 8);
                a1[mt] = *(const half8_t*)(sAl + (wm + mt * 16 + lrow) * BK + quad * 8);
            }
#pragma unroll
            for (int nt = 0; nt < 4; ++nt) {
                b0[nt] = *(const half8_t*)(sBh + (wn + nt * 16 + lrow) * BK + quad * 8);
                b1[nt] = *(const half8_t*)(sBl + (wn + nt * 16 + lrow) * BK + quad * 8);
            }
#pragma unroll
            for (int mt = 0; mt < 4; ++mt)
#pragma unroll
                for (int nt = 0; nt < 4; ++nt) {
                    acc[mt][nt] = __builtin_amdgcn_mfma_f32_16x16x32_f16(a0[mt], b0[nt], acc[mt][nt], 0, 0, 0);
                    acc[mt][nt] = __builtin_amdgcn_mfma_f32_16x16x32_f16(a0[mt], b1[nt], acc[mt][nt], 0, 0, 0);
                    acc[mt][nt] = __builtin_amdgcn_mfma_f32_16x16x32_f16(a1[mt], b0[nt], acc[mt][nt], 0, 0, 0);
                }
            __syncthreads();
        }

#pragma unroll
        for (int pass = 0; pass < 2; ++pass) {
            if (pass) __syncthreads();
#pragma unroll
            for (int mt = 0; mt < 4; ++mt)
#pragma unroll
                for (int nt = 0; nt < 4; ++nt) {
                    int rloc = wm + mt * 16 + quad * 4;
                    int cloc = wn + nt * 16 + lrow;
#pragma unroll
                    for (int r = 0; r < 4; ++r) {
                        float v = acc[mt][nt][r];
                        _Float16 h = (_Float16)v;
                        tle[(rloc + r) * 132 + cloc] =
                            pass == 0 ? h : (_Float16)(v - (float)h);
                    }
                }
            __syncthreads();
            _Float16* dst = pass == 0 ? yh : yl;
#pragma unroll
            for (int i = 0; i < 8; ++i) {
                int flat = i * 256 + tid;
                int rloc = flat >> 4, c = (flat & 15) * 8;
                half8_t o8;
#pragma unroll
                for (int j = 0; j < 8; ++j) o8[j] = tle[rloc * 132 + c + j];
                *(half8_t*)(dst + (size_t)(bm + rloc) * 1024 + bn + c) = o8;
            }
        }
    } else {
        _Float16* sA = (_Float16*)buf;
        _Float16* sB = (_Float16*)(buf + 8192);
        _Float16* lA0 = sA + r0 * BK + kofs;
        _Float16* lA1 = sA + (r0 + 16) * BK + kofs;
        _Float16* lB0 = sB + r0 * BK + kofs;
        _Float16* lB1 = sB + (r0 + 16) * BK + kofs;

        for (int k0 = 0; k0 < 1024; k0 += BK) {
            gl_lds16(xh + a0o + k0, lA0);
            gl_lds16(xh + a1o + k0, lA1);
            gl_lds16(wvTh + b0o + k0, lB0);
            gl_lds16(wvTh + b1o + k0, lB1);
            __syncthreads();

            half8_t a0[4], b0[4];
#pragma unroll
            for (int mt = 0; mt < 4; ++mt)
                a0[mt] = *(const half8_t*)(sA + (wm + mt * 16 + lrow) * BK + quad * 8);
#pragma unroll
            for (int nt = 0; nt < 4; ++nt)
                b0[nt] = *(const half8_t*)(sB + (wn + nt * 16 + lrow) * BK + quad * 8);
#pragma unroll
            for (int mt = 0; mt < 4; ++mt)
#pragma unroll
                for (int nt = 0; nt < 4; ++nt)
                    acc[mt][nt] = __builtin_amdgcn_mfma_f32_16x16x32_f16(a0[mt], b0[nt], acc[mt][nt], 0, 0, 0);
            __syncthreads();
        }

#pragma unroll
        for (int mt = 0; mt < 4; ++mt)
#pragma unroll
            for (int nt = 0; nt < 4; ++nt) {
                int t0 = wm + mt * 16 + quad * 4;
                int e_l = wn + nt * 16 + lrow;
                half4_t o;
#pragma unroll
                for (int r = 0; r < 4; ++r) o[r] = (_Float16)acc[mt][nt][r];
                *(half4_t*)(tle + e_l * 132 + t0) = o;
            }
        __syncthreads();
        const int b = bm >> 11, tb = bm & 2047;
#pragma unroll
        for (int i = 0; i < 8; ++i) {
            int flat = i * 256 + tid;
            int e_l = flat >> 4, c = (flat & 15) * 8;
            half8_t o8;
#pragma unroll
            for (int j = 0; j < 8; ++j) o8[j] = tle[e_l * 132 + c + j];
            *(half8_t*)(vT + ((size_t)b << 21) + (size_t)(bn + e_l) * 2048 + tb + c) = o8;
        }
    }
}

// ---------------- plain-f16 GEMM (16x16x32), 128x128, 256 thr (PV) ----------------
__global__ __launch_bounds__(256) void gemm_plain(
    const _Float16* __restrict__ Ag, size_t az,
    const _Float16* __restrict__ Bg, size_t bz,
    float* __restrict__ Cf, size_t cz, int ldc,
    int lda, int ldb, int K)
{
    __shared__ __align__(16) _Float16 sA[BM][BK], sB[BN][BK];

    const int tid = threadIdx.x;
    const int wave = tid >> 6, lane = tid & 63;
    const int wm = (wave >> 1) * 64, wn = (wave & 1) * 64;
    const int lrow = lane & 15, quad = lane >> 4;
    const int bm = blockIdx.y * BM, bn = blockIdx.x * BN;
    const int z = blockIdx.z;

    const _Float16* pA = Ag + (size_t)z * az;
    const _Float16* pB = Bg + (size_t)z * bz;

    const int r0 = wave * 32 + (lane >> 2);
    const int kofs = (lane & 3) * 8;
    const size_t a0o = (size_t)(bm + r0) * lda + kofs;
    const size_t a1o = a0o + (size_t)16 * lda;
    const size_t b0o = (size_t)(bn + r0) * ldb + kofs;
    const size_t b1o = b0o + (size_t)16 * ldb;
    _Float16* lA0 = &sA[r0][kofs];
    _Float16* lA1 = &sA[r0 + 16][kofs];
    _Float16* lB0 = &sB[r0][kofs];
    _Float16* lB1 = &sB[r0 + 16][kofs];

    f32x4 acc[4][4];
#pragma unroll
    for (int i = 0; i < 4; ++i)
#pragma unroll
        for (int j = 0; j < 4; ++j) acc[i][j] = 0.0f;

    for (int k0 = 0; k0 < K; k0 += BK) {
        gl_lds16(pA + a0o + k0, lA0);
        gl_lds16(pA + a1o + k0, lA1);
        gl_lds16(pB + b0o + k0, lB0);
        gl_lds16(pB + b1o + k0, lB1);
        __syncthreads();

        half8_t a0[4], b0[4];
#pragma unroll
        for (int mt = 0; mt < 4; ++mt)
            a0[mt] = *(const half8_t*)&sA[wm + mt * 16 + lrow][quad * 8];
#pragma unroll
        for (int nt = 0; nt < 4; ++nt)
            b0[nt] = *(const half8_t*)&sB[wn + nt * 16 + lrow][quad * 8];
#pragma unroll
        for (int mt = 0; mt < 4; ++mt)
#pragma unroll
            for (int nt = 0; nt < 4; ++nt)
                acc[mt][nt] = __builtin_amdgcn_mfma_f32_16x16x32_f16(a0[mt], b0[nt], acc[mt][nt], 0, 0, 0);
        __syncthreads();
    }

#pragma unroll
    for (int mt = 0; mt < 4; ++mt)
#pragma unroll
        for (int nt = 0; nt < 4; ++nt) {
            int gm0 = bm + wm + mt * 16 + quad * 4;
            int gn = bn + wn + nt * 16 + lrow;
#pragma unroll
            for (int r = 0; r < 4; ++r)
                Cf[(size_t)z * cz + (size_t)(gm0 + r) * ldc + gn] = acc[mt][nt][r];
        }
}

// ---------------- softmax: fp32 scores row -> f16 P row, in place ----------------
__global__ __launch_bounds__(256) void softmax_kernel(float* __restrict__ S)
{
    float* row = S + (size_t)blockIdx.x * 2048;
    float4* r4 = (float4*)row;
    const int tid = threadIdx.x;
    const int wave = tid >> 6, lane = tid & 63;

    float4 a = r4[tid], b = r4[tid + 256];
    float m = fmaxf(fmaxf(fmaxf(a.x, a.y), fmaxf(a.z, a.w)),
                    fmaxf(fmaxf(b.x, b.y), fmaxf(b.z, b.w)));
#pragma unroll
    for (int o = 32; o; o >>= 1) m = fmaxf(m, __shfl_xor(m, o));
    __shared__ float redm[4];
    __shared__ float reds[4];
    if (lane == 0) redm[wave] = m;
    __syncthreads();
    m = fmaxf(fmaxf(redm[0], redm[1]), fmaxf(redm[2], redm[3]));

    a.x = __expf(a.x - m); a.y = __expf(a.y - m);
    a.z = __expf(a.z - m); a.w = __expf(a.w - m);
    b.x = __expf(b.x - m); b.y = __expf(b.y - m);
    b.z = __expf(b.z - m); b.w = __expf(b.w - m);

    float s = a.x + a.y + a.z + a.w + b.x + b.y + b.z + b.w;
#pragma unroll
    for (int o = 32; o; o >>= 1) s += __shfl_xor(s, o);
    if (lane == 0) reds[wave] = s;
    __syncthreads();
    s = reds[0] + reds[1] + reds[2] + reds[3];

    float inv = 1.0f / s;
    _Float16* o16 = (_Float16*)row;
    half4_t ha, hb;
    ha[0] = (_Float16)(a.x * inv); ha[1] = (_Float16)(a.y * inv);
    ha[2] = (_Float16)(a.z * inv); ha[3] = (_Float16)(a.w * inv);
    hb[0] = (_Float16)(b.x * inv); hb[1] = (_Float16)(b.y * inv);
    hb[2] = (_Float16)(b.z * inv); hb[3] = (_Float16)(b.w * inv);
    ((half4_t*)o16)[tid] = ha;
    ((half4_t*)o16)[tid + 256] = hb;
}

extern "C" void kernel_launch(void* const* d_in, const int* in_sizes, int n_in,
                              void* d_out, int out_size, void* d_ws, size_t ws_size,
                              hipStream_t stream)
{
    const float* x  = (const float*)d_in[0];
    const float* wq = (const float*)d_in[1];
    const float* wk = (const float*)d_in[2];
    const float* wv = (const float*)d_in[3];
    float* out = (float*)d_out;

    const int S = 2048, D = 1024;
    char* ws = (char*)d_ws;

    // ws layout (bytes); high-water 158 MB
    _Float16* xh   = (_Float16*)(ws);                  // 16 MB
    _Float16* xl   = (_Float16*)(ws + (16ull << 20));  // 16 MB
    _Float16* yh   = (_Float16*)(ws + (32ull << 20));  // 16 MB
    _Float16* yl   = (_Float16*)(ws + (48ull << 20));  // 16 MB
    _Float16* vT   = (_Float16*)(ws + (64ull << 20));  // 16 MB [4][1024][2048]
    _Float16* wqh  = (_Float16*)(ws + (80ull << 20));  // 2 MB (natural layout)
    _Float16* wql  = (_Float16*)(ws + (82ull << 20));  // 2 MB
    _Float16* wkh  = (_Float16*)(ws + (84ull << 20));  // 2 MB
    _Float16* wkl  = (_Float16*)(ws + (86ull << 20));  // 2 MB
    _Float16* wvTh = (_Float16*)(ws + (88ull << 20));  // 2 MB (transposed)
    _Float16* Mh   = (_Float16*)(ws + (90ull << 20));  // 2 MB  M' = Wk@Wq^T
    _Float16* Ml   = (_Float16*)(ws + (92ull << 20));  // 2 MB
    float*    sc   = (float*)(ws + (94ull << 20));     // 64 MB scores

    // 1) all conversions, flat grid
    conv_all_kernel<<<dim3(10496), dim3(256), 0, stream>>>(
        x, wq, wk, wv, xh, xl, wqh, wql, wkh, wkl, wvTh);

    // 2) M'[d'][d] = sum_e Wk[d',e]*Wq[d,e]  (split in, split out)
    gemm_split<false><<<dim3(D / BN, D / BM, 1), dim3(256), 0, stream>>>(
        wkh, wkl, 0, wqh, wql, 0, nullptr, 0, 0, Mh, Ml, 0, D, D, D, D);

    // 3) y-proj (split, coalesced epilogue) + v-proj (plain, coalesced vT)
    yv_kernel<<<dim3(D / BN, 8192 / BM, 2), dim3(256), 0, stream>>>(
        xh, xl, Mh, Ml, wvTh, yh, yl, vT);

    // 4) scores over segmented K'=3072, 256x256-tile 8-phase (reg-staged)
    scores_8ph<<<dim3(S / 256, S / 256, 4), dim3(512), 0, stream>>>(
        yh, yl, xh, xl, sc);

    // 5) softmax rows, f16 P written in place (row stride stays 8192 B)
    softmax_kernel<<<dim3(4 * S), dim3(256), 0, stream>>>(sc);

    // 6) out = P @ v: A=P f16 (lda=4096 f16 elems), B=vT f16, out fp32
    gemm_plain<<<dim3(D / BN, S / BM, 4), dim3(256), 0, stream>>>(
        (const _Float16*)sc, (size_t)S * 4096, vT, (size_t)D * S,
        out, (size_t)S * D, D, 4096, S, S);
}

// Round 5
// 391.090 us; speedup vs baseline: 1.0475x; 1.0070x over previous
//
#include <hip/hip_runtime.h>

// AttentionBlock: x[4,2048,1024] fp32; scores = x@(Wq@Wk^T)@x^T (NO scale);
// softmax; out = P@(x@Wv).
// M' = Wk@Wq^T -> y = x@M'^T replaces both q,k projections; scores = y@x^T.
// Split-f16 (hi+lo, 3-MFMA) for M', y, scores; plain f16 for v, PV.
// Round 14: scores_8ph v5 — r13's 1422 cyc/phase = MFMA 621 + LDS 750,
// fully SERIAL: explicit lgkmcnt(0) made every wave drain ALL its ds ops
// before its first MFMA (round-robin LDS arbitration -> all waves finish
// reads at the same late time -> no pipe overlap); 2nd barrier blocked
// cross-phase overlap too. Fix: ONE barrier/phase, NO explicit lgkmcnt —
// compiler emits fine-grained lgkmcnt(N) per MFMA group, first MFMAs start
// while later reads are in flight. Slot-rotation hazard audit: every slot's
// write is >=2 barriers from any read of it (checked per-phase).
// Confirmed dead ends: 128x256 tiles (r4/r5), 32x32x16 MFMA (r6: bank
// conflicts 3x), direct-to-VGPR lo loads (r7), BK=64 in old structure (r6),
// asm "memory"-clobber barriers (r11), gload_lds in 8-phase (r10-r12: DMA
// drain at barriers).

typedef _Float16 half4_t __attribute__((ext_vector_type(4)));
typedef _Float16 half8_t __attribute__((ext_vector_type(8)));
typedef float f32x4 __attribute__((ext_vector_type(4)));

#define BM 128
#define BN 128
#define BK 32

__device__ __forceinline__ void gl_lds16(const _Float16* g, _Float16* l) {
    __builtin_amdgcn_global_load_lds(
        (const __attribute__((address_space(1))) unsigned int*)g,
        (__attribute__((address_space(3))) unsigned int*)l, 16, 0, 0);
}

// ---------------- merged conversion kernel (flat 1D grid) ----------------
__global__ __launch_bounds__(256) void conv_all_kernel(
    const float* __restrict__ x, const float* __restrict__ wq,
    const float* __restrict__ wk, const float* __restrict__ wv,
    _Float16* __restrict__ xh, _Float16* __restrict__ xl,
    _Float16* __restrict__ qh, _Float16* __restrict__ ql,
    _Float16* __restrict__ kh, _Float16* __restrict__ kl,
    _Float16* __restrict__ vTh)
{
    __shared__ float tle[64][65];
    const int bid = blockIdx.x;
    if (bid < 10240) {
        const float* in;
        _Float16 *hi, *lo;
        int i0;
        if (bid < 8192)      { in = x;  hi = xh; lo = xl; i0 = bid; }
        else if (bid < 9216) { in = wq; hi = qh; lo = ql; i0 = bid - 8192; }
        else                 { in = wk; hi = kh; lo = kl; i0 = bid - 9216; }
        int i = i0 * 256 + threadIdx.x;
        float4 v = ((const float4*)in)[i];
        float xs[4] = {v.x, v.y, v.z, v.w};
        half4_t h, l;
#pragma unroll
        for (int j = 0; j < 4; ++j) {
            _Float16 hh = (_Float16)xs[j];
            h[j] = hh;
            l[j] = (_Float16)(xs[j] - (float)hh);
        }
        ((half4_t*)hi)[i] = h;
        ((half4_t*)lo)[i] = l;
    } else {
        const int t = bid - 10240;
        const int tr = (t >> 4) * 64, tc = (t & 15) * 64;
        const int t16 = threadIdx.x & 15, tq = threadIdx.x >> 4;
#pragma unroll
        for (int j = 0; j < 4; ++j) {
            int lr = tq + j * 16;
            float4 v = *(const float4*)(wv + (size_t)(tr + lr) * 1024 + tc + t16 * 4);
            tle[lr][t16 * 4 + 0] = v.x;
            tle[lr][t16 * 4 + 1] = v.y;
            tle[lr][t16 * 4 + 2] = v.z;
            tle[lr][t16 * 4 + 3] = v.w;
        }
        __syncthreads();
#pragma unroll
        for (int j = 0; j < 4; ++j) {
            int orow = tq + j * 16;
            int oc = t16 * 4;
            half4_t h;
#pragma unroll
            for (int i = 0; i < 4; ++i) h[i] = (_Float16)tle[oc + i][orow];
            *(half4_t*)(vTh + (size_t)(tc + orow) * 1024 + tr + oc) = h;
        }
    }
}

// ---------------- split-f16 GEMM (3-MFMA, 16x16x32), 128x128 (M' only) ----------------
template <bool OUTF32>
__global__ __launch_bounds__(256) void gemm_split(
    const _Float16* __restrict__ Ah, const _Float16* __restrict__ Al, size_t az,
    const _Float16* __restrict__ Bh, const _Float16* __restrict__ Bl, size_t bz,
    float* __restrict__ Cf, size_t cz, int ldc,
    _Float16* __restrict__ Oh, _Float16* __restrict__ Ol, size_t oz, int ldo,
    int lda, int ldb, int K)
{
    __shared__ __align__(16) _Float16 sAh[BM][BK], sAl[BM][BK];
    __shared__ __align__(16) _Float16 sBh[BN][BK], sBl[BN][BK];

    const int tid = threadIdx.x;
    const int wave = tid >> 6, lane = tid & 63;
    const int wm = (wave >> 1) * 64, wn = (wave & 1) * 64;
    const int lrow = lane & 15, quad = lane >> 4;
    const int bm = blockIdx.y * BM, bn = blockIdx.x * BN;
    const int z = blockIdx.z;

    const _Float16* pAh = Ah + (size_t)z * az;
    const _Float16* pAl = Al + (size_t)z * az;
    const _Float16* pBh = Bh + (size_t)z * bz;
    const _Float16* pBl = Bl + (size_t)z * bz;

    const int r0 = wave * 32 + (lane >> 2);
    const int kofs = (lane & 3) * 8;
    const size_t a0o = (size_t)(bm + r0) * lda + kofs;
    const size_t a1o = a0o + (size_t)16 * lda;
    const size_t b0o = (size_t)(bn + r0) * ldb + kofs;
    const size_t b1o = b0o + (size_t)16 * ldb;
    _Float16* lA0 = &sAh[r0][kofs];
    _Float16* lA1 = &sAh[r0 + 16][kofs];
    _Float16* lAl0 = &sAl[r0][kofs];
    _Float16* lAl1 = &sAl[r0 + 16][kofs];
    _Float16* lB0 = &sBh[r0][kofs];
    _Float16* lB1 = &sBh[r0 + 16][kofs];
    _Float16* lBl0 = &sBl[r0][kofs];
    _Float16* lBl1 = &sBl[r0 + 16][kofs];

    f32x4 acc[4][4];
#pragma unroll
    for (int i = 0; i < 4; ++i)
#pragma unroll
        for (int j = 0; j < 4; ++j) acc[i][j] = 0.0f;

    for (int k0 = 0; k0 < K; k0 += BK) {
        gl_lds16(pAh + a0o + k0, lA0);
        gl_lds16(pAh + a1o + k0, lA1);
        gl_lds16(pAl + a0o + k0, lAl0);
        gl_lds16(pAl + a1o + k0, lAl1);
        gl_lds16(pBh + b0o + k0, lB0);
        gl_lds16(pBh + b1o + k0, lB1);
        gl_lds16(pBl + b0o + k0, lBl0);
        gl_lds16(pBl + b1o + k0, lBl1);
        __syncthreads();

        half8_t a0[4], a1[4], b0[4], b1[4];
#pragma unroll
        for (int mt = 0; mt < 4; ++mt) {
            a0[mt] = *(const half8_t*)&sAh[wm + mt * 16 + lrow][quad * 8];
            a1[mt] = *(const half8_t*)&sAl[wm + mt * 16 + lrow][quad * 8];
        }
#pragma unroll
        for (int nt = 0; nt < 4; ++nt) {
            b0[nt] = *(const half8_t*)&sBh[wn + nt * 16 + lrow][quad * 8];
            b1[nt] = *(const half8_t*)&sBl[wn + nt * 16 + lrow][quad * 8];
        }
#pragma unroll
        for (int mt = 0; mt < 4; ++mt)
#pragma unroll
            for (int nt = 0; nt < 4; ++nt) {
                acc[mt][nt] = __builtin_amdgcn_mfma_f32_16x16x32_f16(a0[mt], b0[nt], acc[mt][nt], 0, 0, 0);
                acc[mt][nt] = __builtin_amdgcn_mfma_f32_16x16x32_f16(a0[mt], b1[nt], acc[mt][nt], 0, 0, 0);
                acc[mt][nt] = __builtin_amdgcn_mfma_f32_16x16x32_f16(a1[mt], b0[nt], acc[mt][nt], 0, 0, 0);
            }
        __syncthreads();
    }

#pragma unroll
    for (int mt = 0; mt < 4; ++mt)
#pragma unroll
        for (int nt = 0; nt < 4; ++nt)
#pragma unroll
            for (int r = 0; r < 4; ++r) {
                int gm = bm + wm + mt * 16 + quad * 4 + r;
                int gn = bn + wn + nt * 16 + lrow;
                float v = acc[mt][nt][r];
                if (OUTF32) {
                    Cf[(size_t)z * cz + (size_t)gm * ldc + gn] = v;
                } else {
                    _Float16 h = (_Float16)v;
                    Oh[(size_t)z * oz + (size_t)gm * ldo + gn] = h;
                    Ol[(size_t)z * oz + (size_t)gm * ldo + gn] = (_Float16)(v - (float)h);
                }
            }
}

// ---------------- scores: 256x256-tile 8-phase GEMM, segmented K'=3072 ----------------
// v5: single barrier per phase, no explicit lgkmcnt. Per phase:
// {ds_read frags | ds_write one half-tile (regs from 2 phases ago) |
//  issue global_load x2 (+2 phases ahead) | barrier | setprio MFMA}.
// Compiler inserts fine-grained lgkmcnt(N) per MFMA group -> LDS pipe
// overlaps MFMA pipe. Slot rotation: write of any slot is >=2 barriers
// from every read of that slot (audited).
#define NTILES 48  // 3072 / 64

__global__ __launch_bounds__(512, 2) void scores_8ph(
    const _Float16* __restrict__ yh, const _Float16* __restrict__ yl,
    const _Float16* __restrict__ xh, const _Float16* __restrict__ xl,
    float* __restrict__ Cf)
{
    __shared__ __align__(16) _Float16 sA[4][8192];  // 64KB
    __shared__ __align__(16) _Float16 sB[4][8192];  // 64KB

    const int tid = threadIdx.x;
    const int wave = tid >> 6, lane = tid & 63;
    const int wm = (wave >> 2) * 128;      // 2 wave-rows
    const int wn = (wave & 3) * 64;        // 4 wave-cols
    const int l15 = lane & 15, jq = lane >> 4;

    // XCD-chunked bijective swizzle: 256 blocks, XCD = flat%8 gets a
    // contiguous 32-block chunk of work -> A-panels localized to one XCD.
    const int flat = blockIdx.x + (blockIdx.y << 3) + (blockIdx.z << 6);
    const int work = ((flat & 7) << 5) + (flat >> 3);
    const int z = work >> 6;
    const int bm = ((work >> 3) & 7) * 256;
    const int bn = (work & 7) * 256;

    const _Float16* Ah = yh + ((size_t)z * 2048 + bm) * 1024;
    const _Float16* Al = yl + ((size_t)z * 2048 + bm) * 1024;
    const _Float16* Bh = xh + ((size_t)z * 2048 + bn) * 1024;
    const _Float16* Bl = xl + ((size_t)z * 2048 + bn) * 1024;

    // ---- precomputed, asm-pinned per-thread offsets (loop-invariant) ----
    // frag LDS byte offsets: chunk F = row*4 + (jq ^ ((row>>1)&3)), addr F*16
    int a_off[8], b_off[4];
#pragma unroll
    for (int h = 0; h < 2; ++h)
#pragma unroll
        for (int m = 0; m < 4; ++m) {
            int row = wm + h * 64 + m * 16 + l15;
            int F = row * 4 + (jq ^ ((row >> 1) & 3));
            a_off[h * 4 + m] = F * 16;
            asm volatile("" : "+v"(a_off[h * 4 + m]));
        }
#pragma unroll
    for (int n = 0; n < 4; ++n) {
        int row = wn + n * 16 + l15;
        int F = row * 4 + (jq ^ ((row >> 1) & 3));
        b_off[n] = F * 16;
        asm volatile("" : "+v"(b_off[n]));
    }
    // staging: thread covers chunks c0=tid (row tid>>2) and c1=512+tid
    // (row+128; swizzle j identical since 128 ≡ 0 mod 4 after >>1).
    int row0 = tid >> 2;
    int j0 = (tid & 3) ^ ((row0 >> 1) & 3);
    int g0 = row0 * 2048 + j0 * 16;   // global byte offset, chunk c0
    int g1 = g0 + 262144;             // +128 rows, chunk c1
    int wb0 = tid * 16;               // LDS byte offset for chunk c0
    int wb1 = 8192 + tid * 16;        // chunk c1
    asm volatile("" : "+v"(g0), "+v"(g1), "+v"(wb0), "+v"(wb1));

    _Float16* SA0 = sA[0]; _Float16* SA1 = sA[1];
    _Float16* SA2 = sA[2]; _Float16* SA3 = sA[3];
    _Float16* SB0 = sB[0]; _Float16* SB1 = sB[1];
    _Float16* SB2 = sB[2]; _Float16* SB3 = sB[3];

    // in-flight half-tile register sets (2 loads x 16B each)
    f32x4 rAk0[2], rBk0[2], rAk1[2], rBk1[2];

    auto ISSUE = [&](const _Float16* p, f32x4* r) {
        r[0] = *(const f32x4*)((const char*)p + g0);
        r[1] = *(const f32x4*)((const char*)p + g1);
    };
    auto WRITE = [&](const f32x4* r, _Float16* slot) {
        *(f32x4*)((char*)slot + wb0) = r[0];
        *(f32x4*)((char*)slot + wb1) = r[1];
    };
    // segment panel bases (wave-uniform -> SALU): t<32 -> (Ah,*), else Al;
    // B plane: t in [16,32) -> Bl, else Bh.
    auto APAN = [&](int tt, int kh) {
        return (tt < 32 ? Ah : Al) + (tt & 15) * 64 + kh * 32;
    };
    auto BPAN = [&](int tt, int kh) {
        return ((tt >> 4) == 1 ? Bl : Bh) + (tt & 15) * 64 + kh * 32;
    };
    auto RDA = [&](const _Float16* slot, int half, half8_t* dst) {
#pragma unroll
        for (int m = 0; m < 4; ++m)
            dst[m] = *(const half8_t*)((const char*)slot + a_off[half * 4 + m]);
    };
    auto RDB = [&](const _Float16* slot, half8_t* dst) {
#pragma unroll
        for (int n = 0; n < 4; ++n)
            dst[n] = *(const half8_t*)((const char*)slot + b_off[n]);
    };

    f32x4 acc[8][4];
#pragma unroll
    for (int i = 0; i < 8; ++i)
#pragma unroll
        for (int j = 0; j < 4; ++j) acc[i][j] = 0.0f;

    auto MM = [&](half8_t* aa, half8_t* bb, int ah) {
#pragma unroll
        for (int m = 0; m < 4; ++m)
#pragma unroll
            for (int n = 0; n < 4; ++n)
                acc[ah * 4 + m][n] = __builtin_amdgcn_mfma_f32_16x16x32_f16(
                    aa[m], bb[n], acc[ah * 4 + m][n], 0, 0, 0);
    };

#define BARRIER __builtin_amdgcn_s_barrier()
#define P1      __builtin_amdgcn_s_setprio(1)
#define P0      __builtin_amdgcn_s_setprio(0)

    // prologue: tiles 0 (both halves) + 1 (kh0) to LDS; tile1-kh1 left
    // pending in rAk1/rBk1 (written at Eq0/Eq1 of the first iteration).
    ISSUE(APAN(0, 0), rAk0); ISSUE(BPAN(0, 0), rBk0);
    ISSUE(APAN(0, 1), rAk1); ISSUE(BPAN(0, 1), rBk1);
    WRITE(rAk0, SA0); WRITE(rBk0, SB0);
    WRITE(rAk1, SA1); WRITE(rBk1, SB1);
    ISSUE(APAN(1, 0), rAk0); ISSUE(BPAN(1, 0), rBk0);
    WRITE(rAk0, SA2); WRITE(rBk0, SB2);
    ISSUE(APAN(1, 1), rAk1); ISSUE(BPAN(1, 1), rBk1);
    BARRIER;

    for (int t = 0; t < NTILES; t += 2) {
        const int u2 = (t + 2 < NTILES) ? t + 2 : NTILES - 1;  // clamped src
        const int u3 = (t + 3 < NTILES) ? t + 3 : NTILES - 1;  // (dead slots)
        half8_t aa[4], bb[4];

        // ======== even tile t: slots A0/B0 (kh0), A1/B1 (kh1) ========
        // Eq0: write SA3<-(t+1,k1,A); issue (t+2,k0,A)
        RDB(SB0, bb); RDA(SA0, 0, aa);
        WRITE(rAk1, SA3); ISSUE(APAN(u2, 0), rAk0);
        BARRIER; P1; MM(aa, bb, 0); P0;

        // Eq1: write SB3<-(t+1,k1,B); issue (t+2,k0,B)
        RDA(SA0, 1, aa);
        WRITE(rBk1, SB3); ISSUE(BPAN(u2, 0), rBk0);
        BARRIER; P1; MM(aa, bb, 1); P0;

        // Eq2: write SA0<-(t+2,k0,A); issue (t+2,k1,A)
        RDB(SB1, bb); RDA(SA1, 0, aa);
        WRITE(rAk0, SA0); ISSUE(APAN(u2, 1), rAk1);
        BARRIER; P1; MM(aa, bb, 0); P0;

        // Eq3: write SB0<-(t+2,k0,B); issue (t+2,k1,B)
        RDA(SA1, 1, aa);
        WRITE(rBk0, SB0); ISSUE(BPAN(u2, 1), rBk1);
        BARRIER; P1; MM(aa, bb, 1); P0;

        // ======== odd tile t+1: slots A2/B2 (kh0), A3/B3 (kh1) ========
        // Oq0: write SA1<-(t+2,k1,A); issue (t+3,k0,A)
        RDB(SB2, bb); RDA(SA2, 0, aa);
        WRITE(rAk1, SA1); ISSUE(APAN(u3, 0), rAk0);
        BARRIER; P1; MM(aa, bb, 0); P0;

        // Oq1: write SB1<-(t+2,k1,B); issue (t+3,k0,B)
        RDA(SA2, 1, aa);
        WRITE(rBk1, SB1); ISSUE(BPAN(u3, 0), rBk0);
        BARRIER; P1; MM(aa, bb, 1); P0;

        // Oq2: write SA2<-(t+3,k0,A); issue (t+3,k1,A)
        RDB(SB3, bb); RDA(SA3, 0, aa);
        WRITE(rAk0, SA2); ISSUE(APAN(u3, 1), rAk1);
        BARRIER; P1; MM(aa, bb, 0); P0;

        // Oq3: write SB2<-(t+3,k0,B); issue (t+3,k1,B)
        RDA(SA3, 1, aa);
        WRITE(rBk0, SB2); ISSUE(BPAN(u3, 1), rBk1);
        BARRIER; P1; MM(aa, bb, 1); P0;
    }

#undef BARRIER
#undef P1
#undef P0

    // epilogue: fp32 C scatter (same layout as verified gemm_split)
    float* C = Cf + (size_t)z * 2048 * 2048;
#pragma unroll
    for (int mi = 0; mi < 8; ++mi)
#pragma unroll
        for (int ni = 0; ni < 4; ++ni) {
            int gm0 = bm + wm + mi * 16 + jq * 4;
            int gn = bn + wn + ni * 16 + l15;
#pragma unroll
            for (int r = 0; r < 4; ++r)
                C[(size_t)(gm0 + r) * 2048 + gn] = acc[mi][ni][r];
        }
}

// ---------------- merged y-proj (split) + v-proj (plain) kernel ----------------
__global__ __launch_bounds__(256) void yv_kernel(
    const _Float16* __restrict__ xh, const _Float16* __restrict__ xl,
    const _Float16* __restrict__ Mh, const _Float16* __restrict__ Ml,
    const _Float16* __restrict__ wvTh,
    _Float16* __restrict__ yh, _Float16* __restrict__ yl,
    _Float16* __restrict__ vT)
{
    __shared__ __align__(16) char buf[128 * 132 * 2];  // 33792 B

    const int tid = threadIdx.x;
    const int wave = tid >> 6, lane = tid & 63;
    const int wm = (wave >> 1) * 64, wn = (wave & 1) * 64;
    const int lrow = lane & 15, quad = lane >> 4;
    const int bm = blockIdx.y * BM, bn = blockIdx.x * BN;
    const bool vrole = (blockIdx.z != 0);

    const int r0 = wave * 32 + (lane >> 2);
    const int kofs = (lane & 3) * 8;
    const size_t a0o = (size_t)(bm + r0) * 1024 + kofs;
    const size_t a1o = a0o + (size_t)16 * 1024;
    const size_t b0o = (size_t)(bn + r0) * 1024 + kofs;
    const size_t b1o = b0o + (size_t)16 * 1024;

    f32x4 acc[4][4];
#pragma unroll
    for (int i = 0; i < 4; ++i)
#pragma unroll
        for (int j = 0; j < 4; ++j) acc[i][j] = 0.0f;

    _Float16* tle = (_Float16*)buf;

    if (!vrole) {
        _Float16* sAh = (_Float16*)buf;
        _Float16* sAl = (_Float16*)(buf + 8192);
        _Float16* sBh = (_Float16*)(buf + 16384);
        _Float16* sBl = (_Float16*)(buf + 24576);
        _Float16* lA0 = sAh + r0 * BK + kofs;
        _Float16* lA1 = sAh + (r0 + 16) * BK + kofs;
        _Float16* lAl0 = sAl + r0 * BK + kofs;
        _Float16* lAl1 = sAl + (r0 + 16) * BK + kofs;
        _Float16* lB0 = sBh + r0 * BK + kofs;
        _Float16* lB1 = sBh + (r0 + 16) * BK + kofs;
        _Float16* lBl0 = sBl + r0 * BK + kofs;
        _Float16* lBl1 = sBl + (r0 + 16) * BK + kofs;

        for (int k0 = 0; k0 < 1024; k0 += BK) {
            gl_lds16(xh + a0o + k0, lA0);
            gl_lds16(xh + a1o + k0, lA1);
            gl_lds16(xl + a0o + k0, lAl0);
            gl_lds16(xl + a1o + k0, lAl1);
            gl_lds16(Mh + b0o + k0, lB0);
            gl_lds16(Mh + b1o + k0, lB1);
            gl_lds16(Ml + b0o + k0, lBl0);
            gl_lds16(Ml + b1o + k0, lBl1);
            __syncthreads();

            half8_t a0[4], a1[4], b0[4], b1[4];
#pragma unroll
            for (int mt = 0; mt < 4; ++mt) {
                a0[mt] = *(const half8_t*)(sAh + (wm + mt * 16 + lrow) * BK + quad * 8);
                a1[mt] = *(const half8_t*)(sAl + (wm + mt * 16 + lrow) * BK + quad * 8);
            }
#pragma unroll
            for (int nt = 0; nt < 4; ++nt) {
                b0[nt] = *(const half8_t*)(sBh + (wn + nt * 16 + lrow) * BK + quad * 8);
                b1[nt] = *(const half8_t*)(sBl + (wn + nt * 16 + lrow) * BK + quad * 8);
            }
#pragma unroll
            for (int mt = 0; mt < 4; ++mt)
#pragma unroll
                for (int nt = 0; nt < 4; ++nt) {
                    acc[mt][nt] = __builtin_amdgcn_mfma_f32_16x16x32_f16(a0[mt], b0[nt], acc[mt][nt], 0, 0, 0);
                    acc[mt][nt] = __builtin_amdgcn_mfma_f32_16x16x32_f16(a0[mt], b1[nt], acc[mt][nt], 0, 0, 0);
                    acc[mt][nt] = __builtin_amdgcn_mfma_f32_16x16x32_f16(a1[mt], b0[nt], acc[mt][nt], 0, 0, 0);
                }
            __syncthreads();
        }

#pragma unroll
        for (int pass = 0; pass < 2; ++pass) {
            if (pass) __syncthreads();
#pragma unroll
            for (int mt = 0; mt < 4; ++mt)
#pragma unroll
                for (int nt = 0; nt < 4; ++nt) {
                    int rloc = wm + mt * 16 + quad * 4;
                    int cloc = wn + nt * 16 + lrow;
#pragma unroll
                    for (int r = 0; r < 4; ++r) {
                        float v = acc[mt][nt][r];
                        _Float16 h = (_Float16)v;
                        tle[(rloc + r) * 132 + cloc] =
                            pass == 0 ? h : (_Float16)(v - (float)h);
                    }
                }
            __syncthreads();
            _Float16* dst = pass == 0 ? yh : yl;
#pragma unroll
            for (int i = 0; i < 8; ++i) {
                int flat = i * 256 + tid;
                int rloc = flat >> 4, c = (flat & 15) * 8;
                half8_t o8;
#pragma unroll
                for (int j = 0; j < 8; ++j) o8[j] = tle[rloc * 132 + c + j];
                *(half8_t*)(dst + (size_t)(bm + rloc) * 1024 + bn + c) = o8;
            }
        }
    } else {
        _Float16* sA = (_Float16*)buf;
        _Float16* sB = (_Float16*)(buf + 8192);
        _Float16* lA0 = sA + r0 * BK + kofs;
        _Float16* lA1 = sA + (r0 + 16) * BK + kofs;
        _Float16* lB0 = sB + r0 * BK + kofs;
        _Float16* lB1 = sB + (r0 + 16) * BK + kofs;

        for (int k0 = 0; k0 < 1024; k0 += BK) {
            gl_lds16(xh + a0o + k0, lA0);
            gl_lds16(xh + a1o + k0, lA1);
            gl_lds16(wvTh + b0o + k0, lB0);
            gl_lds16(wvTh + b1o + k0, lB1);
            __syncthreads();

            half8_t a0[4], b0[4];
#pragma unroll
            for (int mt = 0; mt < 4; ++mt)
                a0[mt] = *(const half8_t*)(sA + (wm + mt * 16 + lrow) * BK + quad * 8);
#pragma unroll
            for (int nt = 0; nt < 4; ++nt)
                b0[nt] = *(const half8_t*)(sB + (wn + nt * 16 + lrow) * BK + quad * 8);
#pragma unroll
            for (int mt = 0; mt < 4; ++mt)
#pragma unroll
                for (int nt = 0; nt < 4; ++nt)
                    acc[mt][nt] = __builtin_amdgcn_mfma_f32_16x16x32_f16(a0[mt], b0[nt], acc[mt][nt], 0, 0, 0);
            __syncthreads();
        }

#pragma unroll
        for (int mt = 0; mt < 4; ++mt)
#pragma unroll
            for (int nt = 0; nt < 4; ++nt) {
                int t0 = wm + mt * 16 + quad * 4;
                int e_l = wn + nt * 16 + lrow;
                half4_t o;
#pragma unroll
                for (int r = 0; r < 4; ++r) o[r] = (_Float16)acc[mt][nt][r];
                *(half4_t*)(tle + e_l * 132 + t0) = o;
            }
        __syncthreads();
        const int b = bm >> 11, tb = bm & 2047;
#pragma unroll
        for (int i = 0; i < 8; ++i) {
            int flat = i * 256 + tid;
            int e_l = flat >> 4, c = (flat & 15) * 8;
            half8_t o8;
#pragma unroll
            for (int j = 0; j < 8; ++j) o8[j] = tle[e_l * 132 + c + j];
            *(half8_t*)(vT + ((size_t)b << 21) + (size_t)(bn + e_l) * 2048 + tb + c) = o8;
        }
    }
}

// ---------------- plain-f16 GEMM (16x16x32), 128x128, 256 thr (PV) ----------------
__global__ __launch_bounds__(256) void gemm_plain(
    const _Float16* __restrict__ Ag, size_t az,
    const _Float16* __restrict__ Bg, size_t bz,
    float* __restrict__ Cf, size_t cz, int ldc,
    int lda, int ldb, int K)
{
    __shared__ __align__(16) _Float16 sA[BM][BK], sB[BN][BK];

    const int tid = threadIdx.x;
    const int wave = tid >> 6, lane = tid & 63;
    const int wm = (wave >> 1) * 64, wn = (wave & 1) * 64;
    const int lrow = lane & 15, quad = lane >> 4;
    const int bm = blockIdx.y * BM, bn = blockIdx.x * BN;
    const int z = blockIdx.z;

    const _Float16* pA = Ag + (size_t)z * az;
    const _Float16* pB = Bg + (size_t)z * bz;

    const int r0 = wave * 32 + (lane >> 2);
    const int kofs = (lane & 3) * 8;
    const size_t a0o = (size_t)(bm + r0) * lda + kofs;
    const size_t a1o = a0o + (size_t)16 * lda;
    const size_t b0o = (size_t)(bn + r0) * ldb + kofs;
    const size_t b1o = b0o + (size_t)16 * ldb;
    _Float16* lA0 = &sA[r0][kofs];
    _Float16* lA1 = &sA[r0 + 16][kofs];
    _Float16* lB0 = &sB[r0][kofs];
    _Float16* lB1 = &sB[r0 + 16][kofs];

    f32x4 acc[4][4];
#pragma unroll
    for (int i = 0; i < 4; ++i)
#pragma unroll
        for (int j = 0; j < 4; ++j) acc[i][j] = 0.0f;

    for (int k0 = 0; k0 < K; k0 += BK) {
        gl_lds16(pA + a0o + k0, lA0);
        gl_lds16(pA + a1o + k0, lA1);
        gl_lds16(pB + b0o + k0, lB0);
        gl_lds16(pB + b1o + k0, lB1);
        __syncthreads();

        half8_t a0[4], b0[4];
#pragma unroll
        for (int mt = 0; mt < 4; ++mt)
            a0[mt] = *(const half8_t*)&sA[wm + mt * 16 + lrow][quad * 8];
#pragma unroll
        for (int nt = 0; nt < 4; ++nt)
            b0[nt] = *(const half8_t*)&sB[wn + nt * 16 + lrow][quad * 8];
#pragma unroll
        for (int mt = 0; mt < 4; ++mt)
#pragma unroll
            for (int nt = 0; nt < 4; ++nt)
                acc[mt][nt] = __builtin_amdgcn_mfma_f32_16x16x32_f16(a0[mt], b0[nt], acc[mt][nt], 0, 0, 0);
        __syncthreads();
    }

#pragma unroll
    for (int mt = 0; mt < 4; ++mt)
#pragma unroll
        for (int nt = 0; nt < 4; ++nt) {
            int gm0 = bm + wm + mt * 16 + quad * 4;
            int gn = bn + wn + nt * 16 + lrow;
#pragma unroll
            for (int r = 0; r < 4; ++r)
                Cf[(size_t)z * cz + (size_t)(gm0 + r) * ldc + gn] = acc[mt][nt][r];
        }
}

// ---------------- softmax: fp32 scores row -> f16 P row, in place ----------------
__global__ __launch_bounds__(256) void softmax_kernel(float* __restrict__ S)
{
    float* row = S + (size_t)blockIdx.x * 2048;
    float4* r4 = (float4*)row;
    const int tid = threadIdx.x;
    const int wave = tid >> 6, lane = tid & 63;

    float4 a = r4[tid], b = r4[tid + 256];
    float m = fmaxf(fmaxf(fmaxf(a.x, a.y), fmaxf(a.z, a.w)),
                    fmaxf(fmaxf(b.x, b.y), fmaxf(b.z, b.w)));
#pragma unroll
    for (int o = 32; o; o >>= 1) m = fmaxf(m, __shfl_xor(m, o));
    __shared__ float redm[4];
    __shared__ float reds[4];
    if (lane == 0) redm[wave] = m;
    __syncthreads();
    m = fmaxf(fmaxf(redm[0], redm[1]), fmaxf(redm[2], redm[3]));

    a.x = __expf(a.x - m); a.y = __expf(a.y - m);
    a.z = __expf(a.z - m); a.w = __expf(a.w - m);
    b.x = __expf(b.x - m); b.y = __expf(b.y - m);
    b.z = __expf(b.z - m); b.w = __expf(b.w - m);

    float s = a.x + a.y + a.z + a.w + b.x + b.y + b.z + b.w;
#pragma unroll
    for (int o = 32; o; o >>= 1) s += __shfl_xor(s, o);
    if (lane == 0) reds[wave] = s;
    __syncthreads();
    s = reds[0] + reds[1] + reds[2] + reds[3];

    float inv = 1.0f / s;
    _Float16* o16 = (_Float16*)row;
    half4_t ha, hb;
    ha[0] = (_Float16)(a.x * inv); ha[1] = (_Float16)(a.y * inv);
    ha[2] = (_Float16)(a.z * inv); ha[3] = (_Float16)(a.w * inv);
    hb[0] = (_Float16)(b.x * inv); hb[1] = (_Float16)(b.y * inv);
    hb[2] = (_Float16)(b.z * inv); hb[3] = (_Float16)(b.w * inv);
    ((half4_t*)o16)[tid] = ha;
    ((half4_t*)o16)[tid + 256] = hb;
}

extern "C" void kernel_launch(void* const* d_in, const int* in_sizes, int n_in,
                              void* d_out, int out_size, void* d_ws, size_t ws_size,
                              hipStream_t stream)
{
    const float* x  = (const float*)d_in[0];
    const float* wq = (const float*)d_in[1];
    const float* wk = (const float*)d_in[2];
    const float* wv = (const float*)d_in[3];
    float* out = (float*)d_out;

    const int S = 2048, D = 1024;
    char* ws = (char*)d_ws;

    // ws layout (bytes); high-water 158 MB
    _Float16* xh   = (_Float16*)(ws);                  // 16 MB
    _Float16* xl   = (_Float16*)(ws + (16ull << 20));  // 16 MB
    _Float16* yh   = (_Float16*)(ws + (32ull << 20));  // 16 MB
    _Float16* yl   = (_Float16*)(ws + (48ull << 20));  // 16 MB
    _Float16* vT   = (_Float16*)(ws + (64ull << 20));  // 16 MB [4][1024][2048]
    _Float16* wqh  = (_Float16*)(ws + (80ull << 20));  // 2 MB (natural layout)
    _Float16* wql  = (_Float16*)(ws + (82ull << 20));  // 2 MB
    _Float16* wkh  = (_Float16*)(ws + (84ull << 20));  // 2 MB
    _Float16* wkl  = (_Float16*)(ws + (86ull << 20));  // 2 MB
    _Float16* wvTh = (_Float16*)(ws + (88ull << 20));  // 2 MB (transposed)
    _Float16* Mh   = (_Float16*)(ws + (90ull << 20));  // 2 MB  M' = Wk@Wq^T
    _Float16* Ml   = (_Float16*)(ws + (92ull << 20));  // 2 MB
    float*    sc   = (float*)(ws + (94ull << 20));     // 64 MB scores

    // 1) all conversions, flat grid
    conv_all_kernel<<<dim3(10496), dim3(256), 0, stream>>>(
        x, wq, wk, wv, xh, xl, wqh, wql, wkh, wkl, wvTh);

    // 2) M'[d'][d] = sum_e Wk[d',e]*Wq[d,e]  (split in, split out)
    gemm_split<false><<<dim3(D / BN, D / BM, 1), dim3(256), 0, stream>>>(
        wkh, wkl, 0, wqh, wql, 0, nullptr, 0, 0, Mh, Ml, 0, D, D, D, D);

    // 3) y-proj (split, coalesced epilogue) + v-proj (plain, coalesced vT)
    yv_kernel<<<dim3(D / BN, 8192 / BM, 2), dim3(256), 0, stream>>>(
        xh, xl, Mh, Ml, wvTh, yh, yl, vT);

    // 4) scores over segmented K'=3072, 256x256-tile 8-phase (reg-staged,
    //    single-barrier phases, compiler-scheduled waitcnts)
    scores_8ph<<<dim3(S / 256, S / 256, 4), dim3(512), 0, stream>>>(
        yh, yl, xh, xl, sc);

    // 5) softmax rows, f16 P written in place (row stride stays 8192 B)
    softmax_kernel<<<dim3(4 * S), dim3(256), 0, stream>>>(sc);

    // 6) out = P @ v: A=P f16 (lda=4096 f16 elems), B=vT f16, out fp32
    gemm_plain<<<dim3(D / BN, S / BM, 4), dim3(256), 0, stream>>>(
        (const _Float16*)sc, (size_t)S * 4096, vT, (size_t)D * S,
        out, (size_t)S * D, D, 4096, S, S);
}